// Round 23
// baseline (136.907 us; speedup 1.0000x reference)
//
#include <hip/hip_runtime.h>
#include <math.h>

#define N_TOK 4096
#define C_DIM 256
#define HEADS 8
#define HDIM  32
#define SCALE 0.17677669529663687f

typedef float f32x4 __attribute__((ext_vector_type(4)));
typedef float f32x2 __attribute__((ext_vector_type(2)));
typedef int   i32x4 __attribute__((ext_vector_type(4)));
typedef __bf16 bf16x8 __attribute__((ext_vector_type(8)));
typedef __bf16 bf16x2 __attribute__((ext_vector_type(2)));

#if defined(__has_builtin)
#if __has_builtin(__builtin_amdgcn_mfma_f32_16x16x32_bf16)
#define HAVE_MFMA_BUILTIN 1
#endif
#if __has_builtin(__builtin_amdgcn_fdot2_f32_bf16)
#define HAVE_DOT2 1
#endif
#endif

__device__ __forceinline__ unsigned short f2bf(float x){
  unsigned u = __float_as_uint(x);
  u += 0x7FFFu + ((u >> 16) & 1u);
  return (unsigned short)(u >> 16);
}

// packed fragment index: element (row m, col-k k) of a [16 x 32] tile
__device__ __forceinline__ size_t pk_idx(int m, int k, int KT){
  return ((size_t)(m >> 4)*KT + (k >> 5))*512 + (((m & 15) + 16*((k >> 3) & 3))*8 + (k & 7));
}

// order-preserving float->uint (monotone)
__device__ __forceinline__ unsigned f2key(float s){
  unsigned b = __float_as_uint(s);
  return b ^ ((unsigned)((int)b >> 31) | 0x80000000u);
}
__device__ __forceinline__ unsigned umax_(unsigned a, unsigned b){ return a > b ? a : b; }
__device__ __forceinline__ unsigned umin_(unsigned a, unsigned b){ return a < b ? a : b; }

#define KCMP(A,i,j) { unsigned h_ = umax_(A[i],A[j]); unsigned l_ = umin_(A[i],A[j]); A[i]=h_; A[j]=l_; }

__device__ __forceinline__ void sort8(unsigned (&k)[8]){
  KCMP(k,0,1) KCMP(k,2,3) KCMP(k,4,5) KCMP(k,6,7)
  KCMP(k,0,2) KCMP(k,1,3) KCMP(k,4,6) KCMP(k,5,7)
  KCMP(k,1,2) KCMP(k,5,6)
  KCMP(k,0,4) KCMP(k,1,5) KCMP(k,2,6) KCMP(k,3,7)
  KCMP(k,2,4) KCMP(k,3,5)
  KCMP(k,1,2) KCMP(k,3,4) KCMP(k,5,6)
}

__device__ __forceinline__ void mergetop8(unsigned (&a)[8], const unsigned (&b)[8]){
  #pragma unroll
  for (int j=0;j<8;++j) a[j] = umax_(a[j], b[7-j]);
  KCMP(a,0,4) KCMP(a,1,5) KCMP(a,2,6) KCMP(a,3,7)
  KCMP(a,0,2) KCMP(a,1,3) KCMP(a,4,6) KCMP(a,5,7)
  KCMP(a,0,1) KCMP(a,2,3) KCMP(a,4,5) KCMP(a,6,7)
}

template<int MLO, int MHI>
__device__ __forceinline__ void merge_keys(unsigned (&k)[8]){
  #pragma unroll
  for (int m=MLO; m<=MHI; m<<=1){
    unsigned o[8];
    #pragma unroll
    for (int j=0;j<8;++j) o[j] = (unsigned)__shfl_xor((int)k[j], m);
    #pragma unroll
    for (int j=0;j<8;++j) k[j] = umax_(k[j], o[7-j]);
    KCMP(k,0,4) KCMP(k,1,5) KCMP(k,2,6) KCMP(k,3,7)
    KCMP(k,0,2) KCMP(k,1,3) KCMP(k,4,6) KCMP(k,5,7)
    KCMP(k,0,1) KCMP(k,2,3) KCMP(k,4,5) KCMP(k,6,7)
  }
}

// D = A(16x32) * B(32x16) + C via v_mfma_f32_16x16x32_bf16.
__device__ __forceinline__ f32x4 mfma16(i32x4 a, i32x4 b, f32x4 c){
#ifdef HAVE_MFMA_BUILTIN
  return __builtin_amdgcn_mfma_f32_16x16x32_bf16(
      __builtin_bit_cast(bf16x8, a), __builtin_bit_cast(bf16x8, b), c, 0, 0, 0);
#else
  f32x4 d;
  asm volatile("v_mfma_f32_16x16x32_bf16 %0, %1, %2, %3\n\ts_nop 7\n\ts_nop 3"
               : "=&v"(d) : "v"(a), "v"(b), "v"(c));
  return d;
#endif
}

// ---- q-row context + exact f32 dot of a 32-elem bf16 K-row with it ----
#ifdef HAVE_DOT2
struct QCtx { unsigned q[16]; };
__device__ __forceinline__ void qload(QCtx& qc, const unsigned short* qrow){
  #pragma unroll
  for (int i=0;i<4;++i){
    i32x4 qv = *(const i32x4*)(qrow + i*8);
    #pragma unroll
    for (int j=0;j<4;++j) qc.q[i*4+j] = (unsigned)qv[j];
  }
}
__device__ __forceinline__ float dot32(const i32x4& k0, const i32x4& k1,
                                       const i32x4& k2, const i32x4& k3, const QCtx& qc){
  float s = 0.f;
  #pragma unroll
  for (int q=0;q<4;++q){
    const i32x4& kv = (q==0)?k0 : (q==1)?k1 : (q==2)?k2 : k3;
    #pragma unroll
    for (int j=0;j<4;++j)
      s = __builtin_amdgcn_fdot2_f32_bf16(__builtin_bit_cast(bf16x2, (unsigned)kv[j]),
                                          __builtin_bit_cast(bf16x2, qc.q[q*4+j]), s, false);
  }
  return s;
}
#else
struct QCtx { f32x2 q[16]; };
__device__ __forceinline__ void qload(QCtx& qc, const unsigned short* qrow){
  #pragma unroll
  for (int i=0;i<4;++i){
    i32x4 qv = *(const i32x4*)(qrow + i*8);
    #pragma unroll
    for (int j=0;j<4;++j){
      unsigned u = (unsigned)qv[j];
      f32x2 p; p.x = __uint_as_float(u << 16); p.y = __uint_as_float(u & 0xFFFF0000u);
      qc.q[i*4+j] = p;
    }
  }
}
__device__ __forceinline__ float dot32(const i32x4& k0, const i32x4& k1,
                                       const i32x4& k2, const i32x4& k3, const QCtx& qc){
  f32x2 acc = {0.f, 0.f};
  #pragma unroll
  for (int q=0;q<4;++q){
    const i32x4& kv = (q==0)?k0 : (q==1)?k1 : (q==2)?k2 : k3;
    #pragma unroll
    for (int j=0;j<4;++j){
      unsigned u = (unsigned)kv[j];
      f32x2 p; p.x = __uint_as_float(u << 16); p.y = __uint_as_float(u & 0xFFFF0000u);
      acc += p * qc.q[q*4+j];
    }
  }
  return acc.x + acc.y;
}
#endif

// ---------------- LayerNorm (one row of 256 per block), packed bf16 out ----------------
__global__ __launch_bounds__(256) void ln_kernel_pack(const float* __restrict__ x,
    const float* __restrict__ g, const float* __restrict__ b,
    unsigned short* __restrict__ outP)
{
  int row = blockIdx.x, c = threadIdx.x;
  float v = x[(size_t)row*C_DIM + c];
  float s1 = v, s2 = v*v;
  #pragma unroll
  for (int off=1; off<64; off<<=1){
    s1 += __shfl_xor(s1, off);
    s2 += __shfl_xor(s2, off);
  }
  __shared__ float r1[4], r2[4];
  int wv = c >> 6;
  if ((c & 63) == 0){ r1[wv] = s1; r2[wv] = s2; }
  __syncthreads();
  s1 = r1[0]+r1[1]+r1[2]+r1[3];
  s2 = r2[0]+r2[1]+r2[2]+r2[3];
  float mu  = s1 * (1.0f/C_DIM);
  float var = s2 * (1.0f/C_DIM) - mu*mu;
  float inv = 1.0f / sqrtf(var + 1e-5f);
  float o = (v - mu) * inv * g[c] + b[c];
  outP[pk_idx(row, c, 8)] = f2bf(o);
}

// ---------------- LN stats only: one wave per token ----------------
__global__ __launch_bounds__(256) void ln_stats(const float* __restrict__ x,
    float* __restrict__ mu, float* __restrict__ rstd)
{
  int token = blockIdx.x*4 + (threadIdx.x >> 6);
  int lane = threadIdx.x & 63;
  f32x4 v = *(const f32x4*)(x + (size_t)token*C_DIM + lane*4);
  float s1 = v[0]+v[1]+v[2]+v[3];
  float s2 = v[0]*v[0]+v[1]*v[1]+v[2]*v[2]+v[3]*v[3];
  #pragma unroll
  for (int off=1; off<64; off<<=1){
    s1 += __shfl_xor(s1, off);
    s2 += __shfl_xor(s2, off);
  }
  if (lane == 0){
    float m = s1 * (1.0f/C_DIM);
    float var = s2 * (1.0f/C_DIM) - m*m;
    mu[token] = m;
    rstd[token] = 1.0f / sqrtf(var + 1e-5f);
  }
}

// ---------------- fused normalize + 64x64 transpose: x2[tok][ch] -> h2T[ch][tok] ----------------
__global__ __launch_bounds__(256) void transpose_norm(const float* __restrict__ src,
    const float* __restrict__ mu, const float* __restrict__ rstd,
    const float* __restrict__ g, const float* __restrict__ b,
    float* __restrict__ dstF)
{
  __shared__ float t[64][65];
  int c0 = blockIdx.x*64, r0 = blockIdx.y*64;
  int x = threadIdx.x & 63, ys = threadIdx.x >> 6;
  float gg = g[c0 + x], bb = b[c0 + x];
  #pragma unroll
  for (int i=0;i<16;++i){
    int r = ys + i*4;
    int tok = r0 + r;
    float v = src[(size_t)tok*C_DIM + c0 + x];
    t[r][x] = (v - mu[tok]) * rstd[tok] * gg + bb;
  }
  __syncthreads();
  #pragma unroll
  for (int i=0;i<16;++i){
    int rr = ys + i*4;
    dstF[(size_t)(c0+rr)*N_TOK + r0 + x] = t[x][rr];
  }
}

// ---------------- transpose + pack weights: src f32 [K][N]-major -> packed bf16 ----------------
__global__ __launch_bounds__(256) void transpose_pack(const float* __restrict__ src,
    unsigned short* __restrict__ dstP, int Cc, int nbase, int KT)
{
  __shared__ float t[64][65];
  int c0 = blockIdx.x*64, r0 = blockIdx.y*64;
  int x = threadIdx.x & 63, ys = threadIdx.x >> 6;
  #pragma unroll
  for (int i=0;i<16;++i){
    int r = ys + i*4;
    t[r][x] = src[(size_t)(r0+r)*Cc + c0 + x];
  }
  __syncthreads();
  #pragma unroll
  for (int i=0;i<16;++i){
    int rr = ys + i*4;
    int n = nbase + c0 + rr;
    int k = r0 + x;
    dstP[pk_idx(n, k, KT)] = f2bf(t[x][rr]);
  }
}

// ---------------- pack conv1 weights: w1 f32 [256][2048] ([n][k]) -> packed bf16 (KT=64) ----
__global__ __launch_bounds__(256) void pack_w1(const float* __restrict__ w1,
                                               unsigned short* __restrict__ w1p)
{
  int blk = blockIdx.x;          // nt*64 + kt
  int tid = threadIdx.x;
  int lane = tid >> 2;
  int j = (tid & 3) * 2;
  int n = (blk >> 6)*16 + (lane & 15);
  int k = (blk & 63)*32 + (lane >> 4)*8 + j;
  unsigned lo = f2bf(w1[(size_t)n*2048 + k]);
  unsigned hi = f2bf(w1[(size_t)n*2048 + k + 1]);
  *(unsigned*)(w1p + (size_t)blk*512 + lane*8 + j) = lo | (hi << 16);
}

#define LDT(p, i) (*(const i32x4*)((p) + (size_t)(i)*512))

// ---------------- packed-stream GEMM: sequential 1KB/wave tile loads, 4-deep ring ----------------
// NPAIR in {1,2,4}: output tiles per wave from one A stream (A traffic ~ 1/NPAIR).
template<int KTT, int KTC, int NPAIR>
__global__ __launch_bounds__(128, 2) void gemm_packed(
    const unsigned short* __restrict__ Ap, const unsigned short* __restrict__ Bp,
    const float* __restrict__ bias, const float* __restrict__ resid,
    float* __restrict__ outF, float* __restrict__ pbuf)
{
  int wave = threadIdx.x >> 6, lane = threadIdx.x & 63;
  int l16 = lane & 15, lg = lane >> 4;
  int mt = blockIdx.x*2 + wave;
  int nt0 = blockIdx.y * NPAIR;
  int z = blockIdx.z;
  const unsigned short* ap  = Ap + ((size_t)mt*KTT  + z*KTC)*512 + lane*8;
  const unsigned short* bp0 = Bp + ((size_t)nt0*KTT + z*KTC)*512 + lane*8;
  const unsigned short* bp1 = (NPAIR > 1) ? Bp + ((size_t)(nt0+1)*KTT + z*KTC)*512 + lane*8 : bp0;
  const unsigned short* bp2 = (NPAIR > 2) ? Bp + ((size_t)(nt0+2)*KTT + z*KTC)*512 + lane*8 : bp0;
  const unsigned short* bp3 = (NPAIR > 3) ? Bp + ((size_t)(nt0+3)*KTT + z*KTC)*512 + lane*8 : bp0;
  f32x4 acc0 = {0.f,0.f,0.f,0.f}, acc1 = acc0, acc2 = acc0, acc3 = acc0;

  i32x4 A0 = LDT(ap,0), A1 = LDT(ap,1), A2 = LDT(ap,2), A3 = LDT(ap,3);
  i32x4 B0 = LDT(bp0,0), B1 = LDT(bp0,1), B2 = LDT(bp0,2), B3 = LDT(bp0,3);
  i32x4 C0, C1, C2, C3, D0, D1, D2, D3, E0, E1, E2, E3;
  if (NPAIR > 1){ C0 = LDT(bp1,0); C1 = LDT(bp1,1); C2 = LDT(bp1,2); C3 = LDT(bp1,3); }
  if (NPAIR > 2){ D0 = LDT(bp2,0); D1 = LDT(bp2,1); D2 = LDT(bp2,2); D3 = LDT(bp2,3); }
  if (NPAIR > 3){ E0 = LDT(bp3,0); E1 = LDT(bp3,1); E2 = LDT(bp3,2); E3 = LDT(bp3,3); }
  #pragma unroll
  for (int kt = 0; kt < KTC; ++kt){
    const int nk = (kt + 4 < KTC) ? (kt + 4) : (KTC - 1);
    switch (kt & 3){
      case 0: acc0 = mfma16(A0, B0, acc0);
              if (NPAIR > 1) acc1 = mfma16(A0, C0, acc1);
              if (NPAIR > 2) acc2 = mfma16(A0, D0, acc2);
              if (NPAIR > 3) acc3 = mfma16(A0, E0, acc3);
              A0 = LDT(ap,nk); B0 = LDT(bp0,nk);
              if (NPAIR > 1) C0 = LDT(bp1,nk);
              if (NPAIR > 2) D0 = LDT(bp2,nk);
              if (NPAIR > 3) E0 = LDT(bp3,nk);
              break;
      case 1: acc0 = mfma16(A1, B1, acc0);
              if (NPAIR > 1) acc1 = mfma16(A1, C1, acc1);
              if (NPAIR > 2) acc2 = mfma16(A1, D1, acc2);
              if (NPAIR > 3) acc3 = mfma16(A1, E1, acc3);
              A1 = LDT(ap,nk); B1 = LDT(bp0,nk);
              if (NPAIR > 1) C1 = LDT(bp1,nk);
              if (NPAIR > 2) D1 = LDT(bp2,nk);
              if (NPAIR > 3) E1 = LDT(bp3,nk);
              break;
      case 2: acc0 = mfma16(A2, B2, acc0);
              if (NPAIR > 1) acc1 = mfma16(A2, C2, acc1);
              if (NPAIR > 2) acc2 = mfma16(A2, D2, acc2);
              if (NPAIR > 3) acc3 = mfma16(A2, E2, acc3);
              A2 = LDT(ap,nk); B2 = LDT(bp0,nk);
              if (NPAIR > 1) C2 = LDT(bp1,nk);
              if (NPAIR > 2) D2 = LDT(bp2,nk);
              if (NPAIR > 3) E2 = LDT(bp3,nk);
              break;
      case 3: acc0 = mfma16(A3, B3, acc0);
              if (NPAIR > 1) acc1 = mfma16(A3, C3, acc1);
              if (NPAIR > 2) acc2 = mfma16(A3, D3, acc2);
              if (NPAIR > 3) acc3 = mfma16(A3, E3, acc3);
              A3 = LDT(ap,nk); B3 = LDT(bp0,nk);
              if (NPAIR > 1) C3 = LDT(bp1,nk);
              if (NPAIR > 2) D3 = LDT(bp2,nk);
              if (NPAIR > 3) E3 = LDT(bp3,nk);
              break;
    }
  }
  if (pbuf){
    float* pb = pbuf + (size_t)z * (N_TOK*C_DIM);
    #pragma unroll
    for (int f=0; f<NPAIR; ++f){
      f32x4 acc = (f==0)?acc0 : (f==1)?acc1 : (f==2)?acc2 : acc3;
      int n = (nt0 + f)*16 + l16;
      #pragma unroll
      for (int r=0;r<4;++r)
        pb[(size_t)(mt*16 + lg*4 + r)*C_DIM + n] = acc[r];
    }
  } else {
    #pragma unroll
    for (int f=0; f<NPAIR; ++f){
      f32x4 acc = (f==0)?acc0 : (f==1)?acc1 : (f==2)?acc2 : acc3;
      int n = (nt0 + f)*16 + l16;
      float bb = bias[n];
      #pragma unroll
      for (int r=0;r<4;++r){
        int m = mt*16 + lg*4 + r;
        float val = acc[r] + bb;
        if (resid) val += resid[(size_t)m*C_DIM + n];
        outF[(size_t)m*C_DIM + n] = val;
      }
    }
  }
}

// ---------------- fused q/kv/v packed GEMM (paired N-tiles, writes kpack directly) -------
__global__ __launch_bounds__(128, 2) void gemm_qkv_packed(
    const unsigned short* __restrict__ Ap, const unsigned short* __restrict__ Bp,
    const float* __restrict__ q_b, const float* __restrict__ kv_b,
    unsigned short* __restrict__ qbf, unsigned short* __restrict__ kbf,
    float* __restrict__ vbuf, unsigned short* __restrict__ kpackW)
{
  int wave = threadIdx.x >> 6, lane = threadIdx.x & 63;
  int l16 = lane & 15, lg = lane >> 4;
  int mt = blockIdx.x*2 + wave;
  int nt0 = blockIdx.y * 2;
  const unsigned short* ap  = Ap + ((size_t)mt*8)*512 + lane*8;
  const unsigned short* bp0 = Bp + ((size_t)nt0*8)*512 + lane*8;
  const unsigned short* bp1 = Bp + ((size_t)(nt0+1)*8)*512 + lane*8;
  f32x4 acc0 = {0.f,0.f,0.f,0.f}, acc1 = acc0;
  i32x4 A0 = LDT(ap,0), A1 = LDT(ap,1), A2 = LDT(ap,2), A3 = LDT(ap,3);
  i32x4 B0 = LDT(bp0,0), B1 = LDT(bp0,1), B2 = LDT(bp0,2), B3 = LDT(bp0,3);
  i32x4 C0 = LDT(bp1,0), C1 = LDT(bp1,1), C2 = LDT(bp1,2), C3 = LDT(bp1,3);
  #pragma unroll
  for (int kt = 0; kt < 8; ++kt){
    const int nk = (kt + 4 < 8) ? (kt + 4) : 7;
    switch (kt & 3){
      case 0: acc0 = mfma16(A0, B0, acc0); acc1 = mfma16(A0, C0, acc1);
              A0 = LDT(ap,nk); B0 = LDT(bp0,nk); C0 = LDT(bp1,nk); break;
      case 1: acc0 = mfma16(A1, B1, acc0); acc1 = mfma16(A1, C1, acc1);
              A1 = LDT(ap,nk); B1 = LDT(bp0,nk); C1 = LDT(bp1,nk); break;
      case 2: acc0 = mfma16(A2, B2, acc0); acc1 = mfma16(A2, C2, acc1);
              A2 = LDT(ap,nk); B2 = LDT(bp0,nk); C2 = LDT(bp1,nk); break;
      case 3: acc0 = mfma16(A3, B3, acc0); acc1 = mfma16(A3, C3, acc1);
              A3 = LDT(ap,nk); B3 = LDT(bp0,nk); C3 = LDT(bp1,nk); break;
    }
  }
  #pragma unroll
  for (int f=0; f<2; ++f){
    f32x4 acc = f ? acc1 : acc0;
    int n = (nt0 + f)*16 + l16;
    float bb = (n < 256) ? q_b[n] : kv_b[n-256];
    #pragma unroll
    for (int r=0;r<4;++r){
      int m = mt*16 + lg*4 + r;
      float val = acc[r] + bb;
      if (n < 256){
        qbf[(size_t)m*C_DIM + n] = f2bf(fmaxf(val, 0.f));
      } else if (n < 512){
        int ch = n - 256;
        unsigned short bv = f2bf(val);
        kbf[(size_t)m*C_DIM + ch] = bv;
        kpackW[((size_t)((ch >> 5)*256 + mt)*64 + (lg*4 + r) + 16*((ch >> 3) & 3))*8 + (ch & 7)] = bv;
      } else {
        vbuf[(size_t)m*C_DIM + (n-512)] = val;
      }
    }
  }
}

// ---------------- split-K reduce (2 partials): out = p0 + p1 + bias + resid ----------------
__global__ __launch_bounds__(256) void reduce_conv1(const float* __restrict__ pbuf,
    const float* __restrict__ bias, const float* __restrict__ resid,
    float* __restrict__ out)
{
  int i = (blockIdx.x*256 + threadIdx.x) * 4;
  f32x4 a = *(const f32x4*)(pbuf + i);
  f32x4 b = *(const f32x4*)(pbuf + (size_t)N_TOK*C_DIM + i);
  f32x4 r = *(const f32x4*)(resid + i);
  f32x4 bb = *(const f32x4*)(bias + (i & 255));
  *(f32x4*)(out + i) = a + b + r + bb;
}

// ---------------- column sum of v (for closed-form softmax) ----------------
__global__ __launch_bounds__(256) void colsum_part(const float* __restrict__ v, float* __restrict__ part){
  int b = blockIdx.x, c = threadIdx.x;
  float s = 0.f;
  for (int r=0;r<64;++r) s += v[(size_t)(b*64+r)*C_DIM + c];
  part[b*C_DIM + c] = s;
}
__global__ __launch_bounds__(256) void colsum_final(const float* __restrict__ part, float* __restrict__ sumv){
  int c = threadIdx.x;
  float s = 0.f;
  for (int b=0;b<64;++b) s += part[b*C_DIM + c];
  sumv[c] = s;
}

// block = 32 q-rows x 4 waves; wave w scans packed K-tiles [w*64, w*64+64) sequentially,
// 2 q-fragments, 8-deep prefetch ring, IMMEDIATE fold (round-20-proven structure).
__global__ __launch_bounds__(256, 4) void attn_kernel(
    const unsigned short* __restrict__ qbf, const unsigned short* __restrict__ kbf,
    const unsigned short* __restrict__ kpack,
    const float* __restrict__ v, const float* __restrict__ sumv,
    unsigned short* __restrict__ outp)
{
  const int head = blockIdx.y;
  const int tid  = threadIdx.x;
  const int wave = tid >> 6, lane = tid & 63;
  const int l16 = lane & 15, lg = lane >> 4;
  const int row0 = blockIdx.x * 32;

  __shared__ unsigned ls[4][2][16][8];
  __shared__ int   gsel[32][8];
  __shared__ float lds_e[32][8];
  __shared__ int   lds_idx[32][8];
  __shared__ float lds_rd[32];

  // ---- phase 1 ----
  i32x4 qf0 = *(const i32x4*)(qbf + (size_t)(row0      + l16)*C_DIM + head*HDIM + lg*8);
  i32x4 qf1 = *(const i32x4*)(qbf + (size_t)(row0 + 16 + l16)*C_DIM + head*HDIM + lg*8);
  const f32x4 zacc = {0.f,0.f,0.f,0.f};
  const int tbase = wave * 64;
  const unsigned short* kp = kpack + ((size_t)(head*256 + tbase)*64 + lane)*8;

  i32x4 kr0 = *(const i32x4*)(kp);
  i32x4 kr1 = *(const i32x4*)(kp + 512);
  i32x4 kr2 = *(const i32x4*)(kp + 1024);
  i32x4 kr3 = *(const i32x4*)(kp + 1536);
  i32x4 kr4 = *(const i32x4*)(kp + 2048);
  i32x4 kr5 = *(const i32x4*)(kp + 2560);
  i32x4 kr6 = *(const i32x4*)(kp + 3072);
  i32x4 kr7 = *(const i32x4*)(kp + 3584);

  unsigned t0[8], t1[8], g80[8], g81[8];
  #pragma unroll
  for (int j=0;j<8;++j){ t0[j]=0u; t1[j]=0u; }
  const int codebase = 511 - wave*128 - lg;
  #pragma unroll
  for (int g = 0; g < 32; ++g){
    float gm0 = -3e38f, gm1 = -3e38f;
    #pragma unroll
    for (int u = 0; u < 2; ++u){
      const int t = g*2 + u;
      #define USE_SLOT(S) { \
        f32x4 a0 = mfma16(S, qf0, zacc); \
        f32x4 a1 = mfma16(S, qf1, zacc); \
        S = *(const i32x4*)(kp + (size_t)(t+8)*512); \
        gm0 = fmaxf(gm0, fmaxf(fmaxf(a0[0],a0[1]), fmaxf(a0[2],a0[3]))); \
        gm1 = fmaxf(gm1, fmaxf(fmaxf(a1[0],a1[1]), fmaxf(a1[2],a1[3]))); }
      switch (t & 7){
        case 0: USE_SLOT(kr0); break;
        case 1: USE_SLOT(kr1); break;
        case 2: USE_SLOT(kr2); break;
        case 3: USE_SLOT(kr3); break;
        case 4: USE_SLOT(kr4); break;
        case 5: USE_SLOT(kr5); break;
        case 6: USE_SLOT(kr6); break;
        case 7: USE_SLOT(kr7); break;
      }
      #undef USE_SLOT
    }
    unsigned code = (unsigned)(codebase - g*4);
    g80[g & 7] = (f2key(gm0) & 0xFFFFFE00u) | code;
    g81[g & 7] = (f2key(gm1) & 0xFFFFFE00u) | code;
    if ((g & 7) == 7){
      sort8(g80); mergetop8(t0, g80);
      sort8(g81); mergetop8(t1, g81);
    }
  }
  merge_keys<16,32>(t0);
  merge_keys<16,32>(t1);

  if (lg == 0){
    #pragma unroll
    for (int j=0;j<8;++j){ ls[wave][0][l16][j]=t0[j]; ls[wave][1][l16][j]=t1[j]; }
  }
  __syncthreads();

  if (wave < 2){
    unsigned mk[8];
    #pragma unroll
    for (int j=0;j<8;++j) mk[j] = ls[lg][wave][l16][j];
    merge_keys<16,32>(mk);
    if (lg == 0){
      #pragma unroll
      for (int j=0;j<8;++j){
        int gid = 511 - (int)(mk[j] & 511u);
        gsel[wave*16 + l16][j] = (gid >> 2)*32 + (gid & 3)*4;
      }
    }
  }
  __syncthreads();

  // ---- phase 2 ----
  const int prow = tid >> 3;
  const int sub  = tid & 7;
  QCtx qc;
  qload(qc, qbf + (size_t)(row0 + prow)*C_DIM + head*HDIM);
  const int base = gsel[prow][sub];
  const unsigned short* kh = kbf + head*HDIM;
  #define COLOF(c) (base + (((c) >> 2) << 4) + ((c) & 3))
  unsigned sv[8];
  #pragma unroll
  for (int j=0;j<8;++j) sv[j] = 0u;
  i32x4 A0,A1,A2,A3, B0,B1,B2,B3;
  { const unsigned short* p = kh + (size_t)COLOF(0)*C_DIM;
    A0 = *(const i32x4*)(p); A1 = *(const i32x4*)(p+8); A2 = *(const i32x4*)(p+16); A3 = *(const i32x4*)(p+24); }
  { const unsigned short* p = kh + (size_t)COLOF(1)*C_DIM;
    B0 = *(const i32x4*)(p); B1 = *(const i32x4*)(p+8); B2 = *(const i32x4*)(p+16); B3 = *(const i32x4*)(p+24); }
  #pragma unroll
  for (int c = 0; c < 8; ++c){
    float s;
    if ((c & 1) == 0){
      s = dot32(A0,A1,A2,A3, qc);
      if (c + 2 < 8){
        const unsigned short* p = kh + (size_t)COLOF(c+2)*C_DIM;
        A0 = *(const i32x4*)(p); A1 = *(const i32x4*)(p+8); A2 = *(const i32x4*)(p+16); A3 = *(const i32x4*)(p+24);
      }
    } else {
      s = dot32(B0,B1,B2,B3, qc);
      if (c + 2 < 8){
        const unsigned short* p = kh + (size_t)COLOF(c+2)*C_DIM;
        B0 = *(const i32x4*)(p); B1 = *(const i32x4*)(p+8); B2 = *(const i32x4*)(p+16); B3 = *(const i32x4*)(p+24);
      }
    }
    int col = COLOF(c);
    unsigned kk = (f2key(s) & 0xFFFFF000u) | (unsigned)(4095 - col);
    #pragma unroll
    for (int j=0;j<8;++j){ unsigned h = umax_(sv[j], kk); kk = umin_(sv[j], kk); sv[j] = h; }
  }
  #undef COLOF
  merge_keys<1,4>(sv);

  {
    int col = 4095 - (int)(sv[sub] & 4095u);
    const unsigned short* krow = kh + (size_t)col*C_DIM;
    i32x4 k0 = *(const i32x4*)(krow);
    i32x4 k1 = *(const i32x4*)(krow+8);
    i32x4 k2 = *(const i32x4*)(krow+16);
    i32x4 k3 = *(const i32x4*)(krow+24);
    float s = dot32(k0,k1,k2,k3, qc);
    lds_e[prow][sub] = expm1f(s*SCALE);
    lds_idx[prow][sub] = col;
  }
  __syncthreads();

  if (tid < 32){
    float den = 4096.0f;
    #pragma unroll
    for (int j=0;j<8;++j) den += lds_e[tid][j];
    lds_rd[tid] = 1.0f / den;
  }
  __syncthreads();

  // ---- phase 3: PV; write packed fragment layout for proj GEMM ----
  #pragma unroll
  for (int it=0; it<4; ++it){
    int flat = it*256 + tid;
    int rl = flat >> 5, d = flat & 31;
    float num = sumv[head*HDIM + d];
    #pragma unroll
    for (int j=0;j<8;++j)
      num += lds_e[rl][j] * v[(size_t)lds_idx[rl][j]*C_DIM + head*HDIM + d];
    int row = row0 + rl;
    outp[pk_idx(row, head*HDIM + d, 8)] = f2bf(num * lds_rd[rl]);
  }
}

// ---------------- LDS-tiled grouped dwconv 3x3 & 5x5 -> packed A (KT=64) ----------------
__global__ __launch_bounds__(256) void dwconv_tiled(const float* __restrict__ img,
    const float* __restrict__ w3, const float* __restrict__ b3,
    const float* __restrict__ w5, const float* __restrict__ b5,
    unsigned short* __restrict__ apack)
{
  __shared__ float tile[8][513];
  int bx = blockIdx.x;
  int ic0 = bx * 8;
  int py0 = blockIdx.y * 4;
  int tid = threadIdx.x;

  #pragma unroll
  for (int i = 0; i < 16; ++i){
    int idx = i*256 + tid;
    int ch  = idx >> 9;
    int rem = idx & 511;
    int ry  = rem >> 6, x = rem & 63;
    int y   = py0 - 2 + ry;
    float v = (y >= 0 && y < 64) ? img[(size_t)(ic0+ch)*4096 + y*64 + x] : 0.f;
    tile[ch][ry*64 + x] = v;
  }
  __syncthreads();

  int o_l  = tid & 31;
  int p_l  = tid >> 5;
  int ic_l = o_l >> 2;
  int o3   = ic0*4 + o_l;
  const float* pl = tile[ic_l];

  float W3[9], W5[25];
  #pragma unroll
  for (int i=0;i<9;++i)  W3[i] = w3[o3*9+i];
  #pragma unroll
  for (int i=0;i<25;++i) W5[i] = w5[o3*25+i];
  float bb3 = b3[o3], bb5 = b5[o3];

  int lane_lo = 16*((o_l >> 3) & 3);
  int elem    = o_l & 7;

  #pragma unroll 4
  for (int it = 0; it < 32; ++it){
    int pp = it*8 + p_l;
    int ly = (pp >> 6) + 2;
    int x  = pp & 63;
    float a3 = bb3, a5 = bb5;
    #pragma unroll
    for (int dy=-2; dy<=2; ++dy){
      #pragma unroll
      for (int dx=-2; dx<=2; ++dx){
        int xx = x + dx;
        float iv = (xx >= 0 && xx < 64) ? pl[(ly+dy)*64 + xx] : 0.f;
        a5 += W5[(dy+2)*5 + dx+2] * iv;
        if (dy>=-1 && dy<=1 && dx>=-1 && dx<=1)
          a3 += W3[(dy+1)*3 + dx+1] * iv;
      }
    }
    int p = (py0 + (pp>>6))*64 + x;
    size_t ad3 = ((size_t)(p >> 4)*64 + bx)*512 + ((p & 15) + lane_lo)*8 + elem;
    apack[ad3]          = f2bf(fmaxf(a3, 0.f));
    apack[ad3 + 32*512] = f2bf(fmaxf(a5, 0.f));
  }
}

extern "C" void kernel_launch(void* const* d_in, const int* in_sizes, int n_in,
                              void* d_out, int out_size, void* d_ws, size_t ws_size,
                              hipStream_t stream)
{
  (void)in_sizes; (void)n_in; (void)out_size; (void)ws_size;
  const float* x      = (const float*)d_in[0];
  const float* ln1_g  = (const float*)d_in[3];
  const float* ln1_b  = (const float*)d_in[4];
  const float* q_w    = (const float*)d_in[5];
  const float* q_b    = (const float*)d_in[6];
  const float* kv_w   = (const float*)d_in[7];
  const float* kv_b   = (const float*)d_in[8];
  const float* proj_w = (const float*)d_in[9];
  const float* proj_b = (const float*)d_in[10];
  const float* ln2_g  = (const float*)d_in[11];
  const float* ln2_b  = (const float*)d_in[12];
  const float* w3     = (const float*)d_in[13];
  const float* b3     = (const float*)d_in[14];
  const float* w5     = (const float*)d_in[15];
  const float* b5     = (const float*)d_in[16];
  const float* w1     = (const float*)d_in[17];
  const float* b1     = (const float*)d_in[18];
  float* out = (float*)d_out;
  char* ws = (char*)d_ws;

  unsigned short* wAllP = (unsigned short*)(ws + 0x0);       // 384 KB packed qkv weights
  unsigned short* pwP   = (unsigned short*)(ws + 0x60000);   // 128 KB packed proj weights
  unsigned short* w1P   = (unsigned short*)(ws + 0x80000);   // 1 MB packed conv1 weights
  unsigned short* kpack = (unsigned short*)(ws + 0x180000);  // 2 MB (written by qkv; dead after attn)
  unsigned short* qbf   = (unsigned short*)(ws + 0x380000);  // 2 MB row-major
  unsigned short* kbf   = (unsigned short*)(ws + 0x580000);  // 2 MB row-major
  float*          vbuf  = (float*)(ws + 0x780000);           // 4 MB
  unsigned short* opack = (unsigned short*)(ws + 0xB80000);  // 2 MB packed attn out
  float*          x2    = (float*)(ws + 0xD80000);           // 4 MB
  unsigned short* hpack = (unsigned short*)(ws + 0xD80000);  // 2 MB packed ln1 out (dead before x2 written)
  float*          sumv  = (float*)(ws + 0x1180000);          // 1 KB
  float*          part  = (float*)(ws + 0x1190000);          // 64 KB
  float*          mu    = (float*)(ws + 0x11A0000);          // 16 KB
  float*          rstd  = (float*)(ws + 0x11A4000);          // 16 KB
  float*          h2T   = (float*)(ws + 0x580000);           // 4 MB (kbf+vbuf-lo dead after attn)
  float*          pbuf  = (float*)(ws + 0x180000);           // 8 MB (kpack+qbf dead by conv1)
  unsigned short* apack = (unsigned short*)(ws + 0x1200000); // 16 MB packed dwconv out

  dim3 b256(256), b128(128);

  // weight prep (packed)
  pack_w1<<<dim3(1024), b256, 0, stream>>>(w1, w1P);
  transpose_pack<<<dim3(4,4), b256, 0, stream>>>(q_w,   wAllP, 256, 0,   8);
  transpose_pack<<<dim3(8,4), b256, 0, stream>>>(kv_w,  wAllP, 512, 256, 8);
  transpose_pack<<<dim3(4,4), b256, 0, stream>>>(proj_w, pwP,  256, 0,   8);

  // attention branch
  ln_kernel_pack<<<dim3(4096), b256, 0, stream>>>(x, ln1_g, ln1_b, hpack);
  gemm_qkv_packed<<<dim3(128,24), b128, 0, stream>>>(hpack, wAllP, q_b, kv_b, qbf, kbf, vbuf, kpack);
  colsum_part <<<dim3(64), b256, 0, stream>>>(vbuf, part);
  colsum_final<<<dim3(1),  b256, 0, stream>>>(part, sumv);
  attn_kernel<<<dim3(128,8), b256, 0, stream>>>(qbf, kbf, kpack, vbuf, sumv, opack);
  gemm_packed<8,8,2><<<dim3(128,8,1), b128, 0, stream>>>(opack, pwP, proj_b, x, x2, nullptr);

  // MSFN branch (LN2 fused into transpose)
  ln_stats<<<dim3(1024), b256, 0, stream>>>(x2, mu, rstd);
  transpose_norm<<<dim3(4,64), b256, 0, stream>>>(x2, mu, rstd, ln2_g, ln2_b, h2T);
  dwconv_tiled<<<dim3(32,16), b256, 0, stream>>>(h2T, w3, b3, w5, b5, apack);
  gemm_packed<64,32,4><<<dim3(128,4,2), b128, 0, stream>>>(apack, w1P, nullptr, nullptr, nullptr, pbuf);
  reduce_conv1<<<dim3(1024), b256, 0, stream>>>(pbuf, b1, x2, out);
}

// Round 24
// 128.279 us; speedup vs baseline: 1.0673x; 1.0673x over previous
//
#include <hip/hip_runtime.h>
#include <math.h>

#define N_TOK 4096
#define C_DIM 256
#define HEADS 8
#define HDIM  32
#define SCALE 0.17677669529663687f

typedef float f32x4 __attribute__((ext_vector_type(4)));
typedef float f32x2 __attribute__((ext_vector_type(2)));
typedef int   i32x4 __attribute__((ext_vector_type(4)));
typedef __bf16 bf16x8 __attribute__((ext_vector_type(8)));
typedef __bf16 bf16x2 __attribute__((ext_vector_type(2)));

#if defined(__has_builtin)
#if __has_builtin(__builtin_amdgcn_mfma_f32_16x16x32_bf16)
#define HAVE_MFMA_BUILTIN 1
#endif
#if __has_builtin(__builtin_amdgcn_fdot2_f32_bf16)
#define HAVE_DOT2 1
#endif
#endif

__device__ __forceinline__ unsigned short f2bf(float x){
  unsigned u = __float_as_uint(x);
  u += 0x7FFFu + ((u >> 16) & 1u);
  return (unsigned short)(u >> 16);
}

// packed fragment index: element (row m, col-k k) of a [16 x 32] tile
__device__ __forceinline__ size_t pk_idx(int m, int k, int KT){
  return ((size_t)(m >> 4)*KT + (k >> 5))*512 + (((m & 15) + 16*((k >> 3) & 3))*8 + (k & 7));
}

// order-preserving float->uint (monotone)
__device__ __forceinline__ unsigned f2key(float s){
  unsigned b = __float_as_uint(s);
  return b ^ ((unsigned)((int)b >> 31) | 0x80000000u);
}
__device__ __forceinline__ unsigned umax_(unsigned a, unsigned b){ return a > b ? a : b; }
__device__ __forceinline__ unsigned umin_(unsigned a, unsigned b){ return a < b ? a : b; }

#define KCMP(A,i,j) { unsigned h_ = umax_(A[i],A[j]); unsigned l_ = umin_(A[i],A[j]); A[i]=h_; A[j]=l_; }

__device__ __forceinline__ void sort8(unsigned (&k)[8]){
  KCMP(k,0,1) KCMP(k,2,3) KCMP(k,4,5) KCMP(k,6,7)
  KCMP(k,0,2) KCMP(k,1,3) KCMP(k,4,6) KCMP(k,5,7)
  KCMP(k,1,2) KCMP(k,5,6)
  KCMP(k,0,4) KCMP(k,1,5) KCMP(k,2,6) KCMP(k,3,7)
  KCMP(k,2,4) KCMP(k,3,5)
  KCMP(k,1,2) KCMP(k,3,4) KCMP(k,5,6)
}

__device__ __forceinline__ void mergetop8(unsigned (&a)[8], const unsigned (&b)[8]){
  #pragma unroll
  for (int j=0;j<8;++j) a[j] = umax_(a[j], b[7-j]);
  KCMP(a,0,4) KCMP(a,1,5) KCMP(a,2,6) KCMP(a,3,7)
  KCMP(a,0,2) KCMP(a,1,3) KCMP(a,4,6) KCMP(a,5,7)
  KCMP(a,0,1) KCMP(a,2,3) KCMP(a,4,5) KCMP(a,6,7)
}

template<int MLO, int MHI>
__device__ __forceinline__ void merge_keys(unsigned (&k)[8]){
  #pragma unroll
  for (int m=MLO; m<=MHI; m<<=1){
    unsigned o[8];
    #pragma unroll
    for (int j=0;j<8;++j) o[j] = (unsigned)__shfl_xor((int)k[j], m);
    #pragma unroll
    for (int j=0;j<8;++j) k[j] = umax_(k[j], o[7-j]);
    KCMP(k,0,4) KCMP(k,1,5) KCMP(k,2,6) KCMP(k,3,7)
    KCMP(k,0,2) KCMP(k,1,3) KCMP(k,4,6) KCMP(k,5,7)
    KCMP(k,0,1) KCMP(k,2,3) KCMP(k,4,5) KCMP(k,6,7)
  }
}

// D = A(16x32) * B(32x16) + C via v_mfma_f32_16x16x32_bf16.
__device__ __forceinline__ f32x4 mfma16(i32x4 a, i32x4 b, f32x4 c){
#ifdef HAVE_MFMA_BUILTIN
  return __builtin_amdgcn_mfma_f32_16x16x32_bf16(
      __builtin_bit_cast(bf16x8, a), __builtin_bit_cast(bf16x8, b), c, 0, 0, 0);
#else
  f32x4 d;
  asm volatile("v_mfma_f32_16x16x32_bf16 %0, %1, %2, %3\n\ts_nop 7\n\ts_nop 3"
               : "=&v"(d) : "v"(a), "v"(b), "v"(c));
  return d;
#endif
}

// ---- q-row context + exact f32 dot of a 32-elem bf16 K-row with it ----
#ifdef HAVE_DOT2
struct QCtx { unsigned q[16]; };
__device__ __forceinline__ void qload(QCtx& qc, const unsigned short* qrow){
  #pragma unroll
  for (int i=0;i<4;++i){
    i32x4 qv = *(const i32x4*)(qrow + i*8);
    #pragma unroll
    for (int j=0;j<4;++j) qc.q[i*4+j] = (unsigned)qv[j];
  }
}
__device__ __forceinline__ float dot32(const i32x4& k0, const i32x4& k1,
                                       const i32x4& k2, const i32x4& k3, const QCtx& qc){
  float s = 0.f;
  #pragma unroll
  for (int q=0;q<4;++q){
    const i32x4& kv = (q==0)?k0 : (q==1)?k1 : (q==2)?k2 : k3;
    #pragma unroll
    for (int j=0;j<4;++j)
      s = __builtin_amdgcn_fdot2_f32_bf16(__builtin_bit_cast(bf16x2, (unsigned)kv[j]),
                                          __builtin_bit_cast(bf16x2, qc.q[q*4+j]), s, false);
  }
  return s;
}
#else
struct QCtx { f32x2 q[16]; };
__device__ __forceinline__ void qload(QCtx& qc, const unsigned short* qrow){
  #pragma unroll
  for (int i=0;i<4;++i){
    i32x4 qv = *(const i32x4*)(qrow + i*8);
    #pragma unroll
    for (int j=0;j<4;++j){
      unsigned u = (unsigned)qv[j];
      f32x2 p; p.x = __uint_as_float(u << 16); p.y = __uint_as_float(u & 0xFFFF0000u);
      qc.q[i*4+j] = p;
    }
  }
}
__device__ __forceinline__ float dot32(const i32x4& k0, const i32x4& k1,
                                       const i32x4& k2, const i32x4& k3, const QCtx& qc){
  f32x2 acc = {0.f, 0.f};
  #pragma unroll
  for (int q=0;q<4;++q){
    const i32x4& kv = (q==0)?k0 : (q==1)?k1 : (q==2)?k2 : k3;
    #pragma unroll
    for (int j=0;j<4;++j){
      unsigned u = (unsigned)kv[j];
      f32x2 p; p.x = __uint_as_float(u << 16); p.y = __uint_as_float(u & 0xFFFF0000u);
      acc += p * qc.q[q*4+j];
    }
  }
  return acc.x + acc.y;
}
#endif

// ---------------- LayerNorm (one row of 256 per block), packed bf16 out ----------------
__global__ __launch_bounds__(256) void ln_kernel_pack(const float* __restrict__ x,
    const float* __restrict__ g, const float* __restrict__ b,
    unsigned short* __restrict__ outP)
{
  int row = blockIdx.x, c = threadIdx.x;
  float v = x[(size_t)row*C_DIM + c];
  float s1 = v, s2 = v*v;
  #pragma unroll
  for (int off=1; off<64; off<<=1){
    s1 += __shfl_xor(s1, off);
    s2 += __shfl_xor(s2, off);
  }
  __shared__ float r1[4], r2[4];
  int wv = c >> 6;
  if ((c & 63) == 0){ r1[wv] = s1; r2[wv] = s2; }
  __syncthreads();
  s1 = r1[0]+r1[1]+r1[2]+r1[3];
  s2 = r2[0]+r2[1]+r2[2]+r2[3];
  float mu  = s1 * (1.0f/C_DIM);
  float var = s2 * (1.0f/C_DIM) - mu*mu;
  float inv = 1.0f / sqrtf(var + 1e-5f);
  float o = (v - mu) * inv * g[c] + b[c];
  outP[pk_idx(row, c, 8)] = f2bf(o);
}

// ---------------- LN stats only: one wave per token ----------------
__global__ __launch_bounds__(256) void ln_stats(const float* __restrict__ x,
    float* __restrict__ mu, float* __restrict__ rstd)
{
  int token = blockIdx.x*4 + (threadIdx.x >> 6);
  int lane = threadIdx.x & 63;
  f32x4 v = *(const f32x4*)(x + (size_t)token*C_DIM + lane*4);
  float s1 = v[0]+v[1]+v[2]+v[3];
  float s2 = v[0]*v[0]+v[1]*v[1]+v[2]*v[2]+v[3]*v[3];
  #pragma unroll
  for (int off=1; off<64; off<<=1){
    s1 += __shfl_xor(s1, off);
    s2 += __shfl_xor(s2, off);
  }
  if (lane == 0){
    float m = s1 * (1.0f/C_DIM);
    float var = s2 * (1.0f/C_DIM) - m*m;
    mu[token] = m;
    rstd[token] = 1.0f / sqrtf(var + 1e-5f);
  }
}

// ---------------- fused normalize + 64x64 transpose: x2[tok][ch] -> h2T[ch][tok] ----------------
__global__ __launch_bounds__(256) void transpose_norm(const float* __restrict__ src,
    const float* __restrict__ mu, const float* __restrict__ rstd,
    const float* __restrict__ g, const float* __restrict__ b,
    float* __restrict__ dstF)
{
  __shared__ float t[64][65];
  int c0 = blockIdx.x*64, r0 = blockIdx.y*64;
  int x = threadIdx.x & 63, ys = threadIdx.x >> 6;
  float gg = g[c0 + x], bb = b[c0 + x];
  #pragma unroll
  for (int i=0;i<16;++i){
    int r = ys + i*4;
    int tok = r0 + r;
    float v = src[(size_t)tok*C_DIM + c0 + x];
    t[r][x] = (v - mu[tok]) * rstd[tok] * gg + bb;
  }
  __syncthreads();
  #pragma unroll
  for (int i=0;i<16;++i){
    int rr = ys + i*4;
    dstF[(size_t)(c0+rr)*N_TOK + r0 + x] = t[x][rr];
  }
}

// ---------------- fused weight prep: pack_w1 + 3x transpose_pack in one dispatch ----------------
// blocks 0..1023: w1 pack; 1024..1039: q_w; 1040..1071: kv_w; 1072..1087: proj_w
__device__ __forceinline__ void tp_body(const float* __restrict__ src,
    unsigned short* __restrict__ dstP, int Cc, int nbase, int KT, int bx, int by)
{
  __shared__ float t[64][65];
  int c0 = bx*64, r0 = by*64;
  int x = threadIdx.x & 63, ys = threadIdx.x >> 6;
  #pragma unroll
  for (int i=0;i<16;++i){
    int r = ys + i*4;
    t[r][x] = src[(size_t)(r0+r)*Cc + c0 + x];
  }
  __syncthreads();
  #pragma unroll
  for (int i=0;i<16;++i){
    int rr = ys + i*4;
    int n = nbase + c0 + rr;
    int k = r0 + x;
    dstP[pk_idx(n, k, KT)] = f2bf(t[x][rr]);
  }
}

__global__ __launch_bounds__(256) void prep_weights(
    const float* __restrict__ w1, unsigned short* __restrict__ w1p,
    const float* __restrict__ q_w, const float* __restrict__ kv_w,
    const float* __restrict__ proj_w,
    unsigned short* __restrict__ wAllP, unsigned short* __restrict__ pwP)
{
  int b = blockIdx.x;
  if (b < 1024){
    int tid = threadIdx.x;
    int lane = tid >> 2;
    int j = (tid & 3) * 2;
    int n = (b >> 6)*16 + (lane & 15);
    int k = (b & 63)*32 + (lane >> 4)*8 + j;
    unsigned lo = f2bf(w1[(size_t)n*2048 + k]);
    unsigned hi = f2bf(w1[(size_t)n*2048 + k + 1]);
    *(unsigned*)(w1p + (size_t)b*512 + lane*8 + j) = lo | (hi << 16);
  } else if (b < 1040){
    int idx = b - 1024;                       // 4x4: bx = idx&3, by = idx>>2
    tp_body(q_w, wAllP, 256, 0, 8, idx & 3, idx >> 2);
  } else if (b < 1072){
    int idx = b - 1040;                       // 8x4: bx = idx&7, by = idx>>3
    tp_body(kv_w, wAllP, 512, 256, 8, idx & 7, idx >> 3);
  } else {
    int idx = b - 1072;                       // 4x4
    tp_body(proj_w, pwP, 256, 0, 8, idx & 3, idx >> 2);
  }
}

#define LDT(p, i) (*(const i32x4*)((p) + (size_t)(i)*512))

// ---------------- packed-stream GEMM: sequential 1KB/wave tile loads, 4-deep ring ----------------
template<int KTT, int KTC, int NPAIR>
__global__ __launch_bounds__(128, 2) void gemm_packed(
    const unsigned short* __restrict__ Ap, const unsigned short* __restrict__ Bp,
    const float* __restrict__ bias, const float* __restrict__ resid,
    float* __restrict__ outF, float* __restrict__ pbuf)
{
  int wave = threadIdx.x >> 6, lane = threadIdx.x & 63;
  int l16 = lane & 15, lg = lane >> 4;
  int mt = blockIdx.x*2 + wave;
  int nt0 = blockIdx.y * NPAIR;
  int z = blockIdx.z;
  const unsigned short* ap  = Ap + ((size_t)mt*KTT  + z*KTC)*512 + lane*8;
  const unsigned short* bp0 = Bp + ((size_t)nt0*KTT + z*KTC)*512 + lane*8;
  const unsigned short* bp1 = (NPAIR > 1) ? Bp + ((size_t)(nt0+1)*KTT + z*KTC)*512 + lane*8 : bp0;
  f32x4 acc0 = {0.f,0.f,0.f,0.f}, acc1 = acc0;

  i32x4 A0 = LDT(ap,0), A1 = LDT(ap,1), A2 = LDT(ap,2), A3 = LDT(ap,3);
  i32x4 B0 = LDT(bp0,0), B1 = LDT(bp0,1), B2 = LDT(bp0,2), B3 = LDT(bp0,3);
  i32x4 C0, C1, C2, C3;
  if (NPAIR == 2){ C0 = LDT(bp1,0); C1 = LDT(bp1,1); C2 = LDT(bp1,2); C3 = LDT(bp1,3); }
  #pragma unroll
  for (int kt = 0; kt < KTC; ++kt){
    const int nk = (kt + 4 < KTC) ? (kt + 4) : (KTC - 1);
    switch (kt & 3){
      case 0: acc0 = mfma16(A0, B0, acc0); if (NPAIR==2) acc1 = mfma16(A0, C0, acc1);
              A0 = LDT(ap,nk); B0 = LDT(bp0,nk); if (NPAIR==2) C0 = LDT(bp1,nk); break;
      case 1: acc0 = mfma16(A1, B1, acc0); if (NPAIR==2) acc1 = mfma16(A1, C1, acc1);
              A1 = LDT(ap,nk); B1 = LDT(bp0,nk); if (NPAIR==2) C1 = LDT(bp1,nk); break;
      case 2: acc0 = mfma16(A2, B2, acc0); if (NPAIR==2) acc1 = mfma16(A2, C2, acc1);
              A2 = LDT(ap,nk); B2 = LDT(bp0,nk); if (NPAIR==2) C2 = LDT(bp1,nk); break;
      case 3: acc0 = mfma16(A3, B3, acc0); if (NPAIR==2) acc1 = mfma16(A3, C3, acc1);
              A3 = LDT(ap,nk); B3 = LDT(bp0,nk); if (NPAIR==2) C3 = LDT(bp1,nk); break;
    }
  }
  if (pbuf){
    float* pb = pbuf + (size_t)z * (N_TOK*C_DIM);
    #pragma unroll
    for (int f=0; f<NPAIR; ++f){
      f32x4 acc = f ? acc1 : acc0;
      int n = (nt0 + f)*16 + l16;
      #pragma unroll
      for (int r=0;r<4;++r)
        pb[(size_t)(mt*16 + lg*4 + r)*C_DIM + n] = acc[r];
    }
  } else {
    #pragma unroll
    for (int f=0; f<NPAIR; ++f){
      f32x4 acc = f ? acc1 : acc0;
      int n = (nt0 + f)*16 + l16;
      float bb = bias[n];
      #pragma unroll
      for (int r=0;r<4;++r){
        int m = mt*16 + lg*4 + r;
        float val = acc[r] + bb;
        if (resid) val += resid[(size_t)m*C_DIM + n];
        outF[(size_t)m*C_DIM + n] = val;
      }
    }
  }
}

// ---------------- fused q/kv/v packed GEMM (paired N-tiles, writes kpack directly) -------
__global__ __launch_bounds__(128, 2) void gemm_qkv_packed(
    const unsigned short* __restrict__ Ap, const unsigned short* __restrict__ Bp,
    const float* __restrict__ q_b, const float* __restrict__ kv_b,
    unsigned short* __restrict__ qbf, unsigned short* __restrict__ kbf,
    float* __restrict__ vbuf, unsigned short* __restrict__ kpackW)
{
  int wave = threadIdx.x >> 6, lane = threadIdx.x & 63;
  int l16 = lane & 15, lg = lane >> 4;
  int mt = blockIdx.x*2 + wave;
  int nt0 = blockIdx.y * 2;
  const unsigned short* ap  = Ap + ((size_t)mt*8)*512 + lane*8;
  const unsigned short* bp0 = Bp + ((size_t)nt0*8)*512 + lane*8;
  const unsigned short* bp1 = Bp + ((size_t)(nt0+1)*8)*512 + lane*8;
  f32x4 acc0 = {0.f,0.f,0.f,0.f}, acc1 = acc0;
  i32x4 A0 = LDT(ap,0), A1 = LDT(ap,1), A2 = LDT(ap,2), A3 = LDT(ap,3);
  i32x4 B0 = LDT(bp0,0), B1 = LDT(bp0,1), B2 = LDT(bp0,2), B3 = LDT(bp0,3);
  i32x4 C0 = LDT(bp1,0), C1 = LDT(bp1,1), C2 = LDT(bp1,2), C3 = LDT(bp1,3);
  #pragma unroll
  for (int kt = 0; kt < 8; ++kt){
    const int nk = (kt + 4 < 8) ? (kt + 4) : 7;
    switch (kt & 3){
      case 0: acc0 = mfma16(A0, B0, acc0); acc1 = mfma16(A0, C0, acc1);
              A0 = LDT(ap,nk); B0 = LDT(bp0,nk); C0 = LDT(bp1,nk); break;
      case 1: acc0 = mfma16(A1, B1, acc0); acc1 = mfma16(A1, C1, acc1);
              A1 = LDT(ap,nk); B1 = LDT(bp0,nk); C1 = LDT(bp1,nk); break;
      case 2: acc0 = mfma16(A2, B2, acc0); acc1 = mfma16(A2, C2, acc1);
              A2 = LDT(ap,nk); B2 = LDT(bp0,nk); C2 = LDT(bp1,nk); break;
      case 3: acc0 = mfma16(A3, B3, acc0); acc1 = mfma16(A3, C3, acc1);
              A3 = LDT(ap,nk); B3 = LDT(bp0,nk); C3 = LDT(bp1,nk); break;
    }
  }
  #pragma unroll
  for (int f=0; f<2; ++f){
    f32x4 acc = f ? acc1 : acc0;
    int n = (nt0 + f)*16 + l16;
    float bb = (n < 256) ? q_b[n] : kv_b[n-256];
    #pragma unroll
    for (int r=0;r<4;++r){
      int m = mt*16 + lg*4 + r;
      float val = acc[r] + bb;
      if (n < 256){
        qbf[(size_t)m*C_DIM + n] = f2bf(fmaxf(val, 0.f));
      } else if (n < 512){
        int ch = n - 256;
        unsigned short bv = f2bf(val);
        kbf[(size_t)m*C_DIM + ch] = bv;
        kpackW[((size_t)((ch >> 5)*256 + mt)*64 + (lg*4 + r) + 16*((ch >> 3) & 3))*8 + (ch & 7)] = bv;
      } else {
        vbuf[(size_t)m*C_DIM + (n-512)] = val;
      }
    }
  }
}

// ---------------- split-K reduce (2 partials): out = p0 + p1 + bias + resid ----------------
__global__ __launch_bounds__(256) void reduce_conv1(const float* __restrict__ pbuf,
    const float* __restrict__ bias, const float* __restrict__ resid,
    float* __restrict__ out)
{
  int i = (blockIdx.x*256 + threadIdx.x) * 4;
  f32x4 a = *(const f32x4*)(pbuf + i);
  f32x4 b = *(const f32x4*)(pbuf + (size_t)N_TOK*C_DIM + i);
  f32x4 r = *(const f32x4*)(resid + i);
  f32x4 bb = *(const f32x4*)(bias + (i & 255));
  *(f32x4*)(out + i) = a + b + r + bb;
}

// ---------------- column sum of v (for closed-form softmax) ----------------
__global__ __launch_bounds__(256) void colsum_part(const float* __restrict__ v, float* __restrict__ part){
  int b = blockIdx.x, c = threadIdx.x;
  float s = 0.f;
  for (int r=0;r<64;++r) s += v[(size_t)(b*64+r)*C_DIM + c];
  part[b*C_DIM + c] = s;
}
__global__ __launch_bounds__(256) void colsum_final(const float* __restrict__ part, float* __restrict__ sumv){
  int c = threadIdx.x;
  float s = 0.f;
  for (int b=0;b<64;++b) s += part[b*C_DIM + c];
  sumv[c] = s;
}

// block = 32 q-rows x 4 waves; wave w scans packed K-tiles [w*64, w*64+64) sequentially,
// 2 q-fragments, 8-deep prefetch ring, IMMEDIATE fold (round-20-proven structure).
__global__ __launch_bounds__(256, 4) void attn_kernel(
    const unsigned short* __restrict__ qbf, const unsigned short* __restrict__ kbf,
    const unsigned short* __restrict__ kpack,
    const float* __restrict__ v, const float* __restrict__ sumv,
    unsigned short* __restrict__ outp)
{
  const int head = blockIdx.y;
  const int tid  = threadIdx.x;
  const int wave = tid >> 6, lane = tid & 63;
  const int l16 = lane & 15, lg = lane >> 4;
  const int row0 = blockIdx.x * 32;

  __shared__ unsigned ls[4][2][16][8];
  __shared__ int   gsel[32][8];
  __shared__ float lds_e[32][8];
  __shared__ int   lds_idx[32][8];
  __shared__ float lds_rd[32];

  // ---- phase 1 ----
  i32x4 qf0 = *(const i32x4*)(qbf + (size_t)(row0      + l16)*C_DIM + head*HDIM + lg*8);
  i32x4 qf1 = *(const i32x4*)(qbf + (size_t)(row0 + 16 + l16)*C_DIM + head*HDIM + lg*8);
  const f32x4 zacc = {0.f,0.f,0.f,0.f};
  const int tbase = wave * 64;
  const unsigned short* kp = kpack + ((size_t)(head*256 + tbase)*64 + lane)*8;

  i32x4 kr0 = *(const i32x4*)(kp);
  i32x4 kr1 = *(const i32x4*)(kp + 512);
  i32x4 kr2 = *(const i32x4*)(kp + 1024);
  i32x4 kr3 = *(const i32x4*)(kp + 1536);
  i32x4 kr4 = *(const i32x4*)(kp + 2048);
  i32x4 kr5 = *(const i32x4*)(kp + 2560);
  i32x4 kr6 = *(const i32x4*)(kp + 3072);
  i32x4 kr7 = *(const i32x4*)(kp + 3584);

  unsigned t0[8], t1[8], g80[8], g81[8];
  #pragma unroll
  for (int j=0;j<8;++j){ t0[j]=0u; t1[j]=0u; }
  const int codebase = 511 - wave*128 - lg;
  #pragma unroll
  for (int g = 0; g < 32; ++g){
    float gm0 = -3e38f, gm1 = -3e38f;
    #pragma unroll
    for (int u = 0; u < 2; ++u){
      const int t = g*2 + u;
      #define USE_SLOT(S) { \
        f32x4 a0 = mfma16(S, qf0, zacc); \
        f32x4 a1 = mfma16(S, qf1, zacc); \
        S = *(const i32x4*)(kp + (size_t)(t+8)*512); \
        gm0 = fmaxf(gm0, fmaxf(fmaxf(a0[0],a0[1]), fmaxf(a0[2],a0[3]))); \
        gm1 = fmaxf(gm1, fmaxf(fmaxf(a1[0],a1[1]), fmaxf(a1[2],a1[3]))); }
      switch (t & 7){
        case 0: USE_SLOT(kr0); break;
        case 1: USE_SLOT(kr1); break;
        case 2: USE_SLOT(kr2); break;
        case 3: USE_SLOT(kr3); break;
        case 4: USE_SLOT(kr4); break;
        case 5: USE_SLOT(kr5); break;
        case 6: USE_SLOT(kr6); break;
        case 7: USE_SLOT(kr7); break;
      }
      #undef USE_SLOT
    }
    unsigned code = (unsigned)(codebase - g*4);
    g80[g & 7] = (f2key(gm0) & 0xFFFFFE00u) | code;
    g81[g & 7] = (f2key(gm1) & 0xFFFFFE00u) | code;
    if ((g & 7) == 7){
      sort8(g80); mergetop8(t0, g80);
      sort8(g81); mergetop8(t1, g81);
    }
  }
  merge_keys<16,32>(t0);
  merge_keys<16,32>(t1);

  if (lg == 0){
    #pragma unroll
    for (int j=0;j<8;++j){ ls[wave][0][l16][j]=t0[j]; ls[wave][1][l16][j]=t1[j]; }
  }
  __syncthreads();

  if (wave < 2){
    unsigned mk[8];
    #pragma unroll
    for (int j=0;j<8;++j) mk[j] = ls[lg][wave][l16][j];
    merge_keys<16,32>(mk);
    if (lg == 0){
      #pragma unroll
      for (int j=0;j<8;++j){
        int gid = 511 - (int)(mk[j] & 511u);
        gsel[wave*16 + l16][j] = (gid >> 2)*32 + (gid & 3)*4;
      }
    }
  }
  __syncthreads();

  // ---- phase 2 ----
  const int prow = tid >> 3;
  const int sub  = tid & 7;
  QCtx qc;
  qload(qc, qbf + (size_t)(row0 + prow)*C_DIM + head*HDIM);
  const int base = gsel[prow][sub];
  const unsigned short* kh = kbf + head*HDIM;
  #define COLOF(c) (base + (((c) >> 2) << 4) + ((c) & 3))
  unsigned sv[8];
  #pragma unroll
  for (int j=0;j<8;++j) sv[j] = 0u;
  i32x4 A0,A1,A2,A3, B0,B1,B2,B3;
  { const unsigned short* p = kh + (size_t)COLOF(0)*C_DIM;
    A0 = *(const i32x4*)(p); A1 = *(const i32x4*)(p+8); A2 = *(const i32x4*)(p+16); A3 = *(const i32x4*)(p+24); }
  { const unsigned short* p = kh + (size_t)COLOF(1)*C_DIM;
    B0 = *(const i32x4*)(p); B1 = *(const i32x4*)(p+8); B2 = *(const i32x4*)(p+16); B3 = *(const i32x4*)(p+24); }
  #pragma unroll
  for (int c = 0; c < 8; ++c){
    float s;
    if ((c & 1) == 0){
      s = dot32(A0,A1,A2,A3, qc);
      if (c + 2 < 8){
        const unsigned short* p = kh + (size_t)COLOF(c+2)*C_DIM;
        A0 = *(const i32x4*)(p); A1 = *(const i32x4*)(p+8); A2 = *(const i32x4*)(p+16); A3 = *(const i32x4*)(p+24);
      }
    } else {
      s = dot32(B0,B1,B2,B3, qc);
      if (c + 2 < 8){
        const unsigned short* p = kh + (size_t)COLOF(c+2)*C_DIM;
        B0 = *(const i32x4*)(p); B1 = *(const i32x4*)(p+8); B2 = *(const i32x4*)(p+16); B3 = *(const i32x4*)(p+24);
      }
    }
    int col = COLOF(c);
    unsigned kk = (f2key(s) & 0xFFFFF000u) | (unsigned)(4095 - col);
    #pragma unroll
    for (int j=0;j<8;++j){ unsigned h = umax_(sv[j], kk); kk = umin_(sv[j], kk); sv[j] = h; }
  }
  #undef COLOF
  merge_keys<1,4>(sv);

  {
    int col = 4095 - (int)(sv[sub] & 4095u);
    const unsigned short* krow = kh + (size_t)col*C_DIM;
    i32x4 k0 = *(const i32x4*)(krow);
    i32x4 k1 = *(const i32x4*)(krow+8);
    i32x4 k2 = *(const i32x4*)(krow+16);
    i32x4 k3 = *(const i32x4*)(krow+24);
    float s = dot32(k0,k1,k2,k3, qc);
    lds_e[prow][sub] = expm1f(s*SCALE);
    lds_idx[prow][sub] = col;
  }
  __syncthreads();

  if (tid < 32){
    float den = 4096.0f;
    #pragma unroll
    for (int j=0;j<8;++j) den += lds_e[tid][j];
    lds_rd[tid] = 1.0f / den;
  }
  __syncthreads();

  // ---- phase 3: PV; write packed fragment layout for proj GEMM ----
  #pragma unroll
  for (int it=0; it<4; ++it){
    int flat = it*256 + tid;
    int rl = flat >> 5, d = flat & 31;
    float num = sumv[head*HDIM + d];
    #pragma unroll
    for (int j=0;j<8;++j)
      num += lds_e[rl][j] * v[(size_t)lds_idx[rl][j]*C_DIM + head*HDIM + d];
    int row = row0 + rl;
    outp[pk_idx(row, head*HDIM + d, 8)] = f2bf(num * lds_rd[rl]);
  }
}

// ---------------- LDS-tiled grouped dwconv 3x3 & 5x5 -> packed A (KT=64) ----------------
__global__ __launch_bounds__(256) void dwconv_tiled(const float* __restrict__ img,
    const float* __restrict__ w3, const float* __restrict__ b3,
    const float* __restrict__ w5, const float* __restrict__ b5,
    unsigned short* __restrict__ apack)
{
  __shared__ float tile[8][513];
  int bx = blockIdx.x;
  int ic0 = bx * 8;
  int py0 = blockIdx.y * 4;
  int tid = threadIdx.x;

  #pragma unroll
  for (int i = 0; i < 16; ++i){
    int idx = i*256 + tid;
    int ch  = idx >> 9;
    int rem = idx & 511;
    int ry  = rem >> 6, x = rem & 63;
    int y   = py0 - 2 + ry;
    float v = (y >= 0 && y < 64) ? img[(size_t)(ic0+ch)*4096 + y*64 + x] : 0.f;
    tile[ch][ry*64 + x] = v;
  }
  __syncthreads();

  int o_l  = tid & 31;
  int p_l  = tid >> 5;
  int ic_l = o_l >> 2;
  int o3   = ic0*4 + o_l;
  const float* pl = tile[ic_l];

  float W3[9], W5[25];
  #pragma unroll
  for (int i=0;i<9;++i)  W3[i] = w3[o3*9+i];
  #pragma unroll
  for (int i=0;i<25;++i) W5[i] = w5[o3*25+i];
  float bb3 = b3[o3], bb5 = b5[o3];

  int lane_lo = 16*((o_l >> 3) & 3);
  int elem    = o_l & 7;

  #pragma unroll 4
  for (int it = 0; it < 32; ++it){
    int pp = it*8 + p_l;
    int ly = (pp >> 6) + 2;
    int x  = pp & 63;
    float a3 = bb3, a5 = bb5;
    #pragma unroll
    for (int dy=-2; dy<=2; ++dy){
      #pragma unroll
      for (int dx=-2; dx<=2; ++dx){
        int xx = x + dx;
        float iv = (xx >= 0 && xx < 64) ? pl[(ly+dy)*64 + xx] : 0.f;
        a5 += W5[(dy+2)*5 + dx+2] * iv;
        if (dy>=-1 && dy<=1 && dx>=-1 && dx<=1)
          a3 += W3[(dy+1)*3 + dx+1] * iv;
      }
    }
    int p = (py0 + (pp>>6))*64 + x;
    size_t ad3 = ((size_t)(p >> 4)*64 + bx)*512 + ((p & 15) + lane_lo)*8 + elem;
    apack[ad3]          = f2bf(fmaxf(a3, 0.f));
    apack[ad3 + 32*512] = f2bf(fmaxf(a5, 0.f));
  }
}

extern "C" void kernel_launch(void* const* d_in, const int* in_sizes, int n_in,
                              void* d_out, int out_size, void* d_ws, size_t ws_size,
                              hipStream_t stream)
{
  (void)in_sizes; (void)n_in; (void)out_size; (void)ws_size;
  const float* x      = (const float*)d_in[0];
  const float* ln1_g  = (const float*)d_in[3];
  const float* ln1_b  = (const float*)d_in[4];
  const float* q_w    = (const float*)d_in[5];
  const float* q_b    = (const float*)d_in[6];
  const float* kv_w   = (const float*)d_in[7];
  const float* kv_b   = (const float*)d_in[8];
  const float* proj_w = (const float*)d_in[9];
  const float* proj_b = (const float*)d_in[10];
  const float* ln2_g  = (const float*)d_in[11];
  const float* ln2_b  = (const float*)d_in[12];
  const float* w3     = (const float*)d_in[13];
  const float* b3     = (const float*)d_in[14];
  const float* w5     = (const float*)d_in[15];
  const float* b5     = (const float*)d_in[16];
  const float* w1     = (const float*)d_in[17];
  const float* b1     = (const float*)d_in[18];
  float* out = (float*)d_out;
  char* ws = (char*)d_ws;

  unsigned short* wAllP = (unsigned short*)(ws + 0x0);       // 384 KB packed qkv weights
  unsigned short* pwP   = (unsigned short*)(ws + 0x60000);   // 128 KB packed proj weights
  unsigned short* w1P   = (unsigned short*)(ws + 0x80000);   // 1 MB packed conv1 weights
  unsigned short* kpack = (unsigned short*)(ws + 0x180000);  // 2 MB (written by qkv; dead after attn)
  unsigned short* qbf   = (unsigned short*)(ws + 0x380000);  // 2 MB row-major
  unsigned short* kbf   = (unsigned short*)(ws + 0x580000);  // 2 MB row-major
  float*          vbuf  = (float*)(ws + 0x780000);           // 4 MB
  unsigned short* opack = (unsigned short*)(ws + 0xB80000);  // 2 MB packed attn out
  float*          x2    = (float*)(ws + 0xD80000);           // 4 MB
  unsigned short* hpack = (unsigned short*)(ws + 0xD80000);  // 2 MB packed ln1 out (dead before x2 written)
  float*          sumv  = (float*)(ws + 0x1180000);          // 1 KB
  float*          part  = (float*)(ws + 0x1190000);          // 64 KB
  float*          mu    = (float*)(ws + 0x11A0000);          // 16 KB
  float*          rstd  = (float*)(ws + 0x11A4000);          // 16 KB
  float*          h2T   = (float*)(ws + 0x580000);           // 4 MB (kbf+vbuf-lo dead after attn)
  float*          pbuf  = (float*)(ws + 0x180000);           // 8 MB (kpack+qbf dead by conv1)
  unsigned short* apack = (unsigned short*)(ws + 0x1200000); // 16 MB packed dwconv out

  dim3 b256(256), b128(128);

  // fused weight prep (1 dispatch instead of 4)
  prep_weights<<<dim3(1088), b256, 0, stream>>>(w1, w1P, q_w, kv_w, proj_w, wAllP, pwP);

  // attention branch
  ln_kernel_pack<<<dim3(4096), b256, 0, stream>>>(x, ln1_g, ln1_b, hpack);
  gemm_qkv_packed<<<dim3(128,24), b128, 0, stream>>>(hpack, wAllP, q_b, kv_b, qbf, kbf, vbuf, kpack);
  colsum_part <<<dim3(64), b256, 0, stream>>>(vbuf, part);
  colsum_final<<<dim3(1),  b256, 0, stream>>>(part, sumv);
  attn_kernel<<<dim3(128,8), b256, 0, stream>>>(qbf, kbf, kpack, vbuf, sumv, opack);
  gemm_packed<8,8,2><<<dim3(128,8,1), b128, 0, stream>>>(opack, pwP, proj_b, x, x2, nullptr);

  // MSFN branch (LN2 fused into transpose)
  ln_stats<<<dim3(1024), b256, 0, stream>>>(x2, mu, rstd);
  transpose_norm<<<dim3(4,64), b256, 0, stream>>>(x2, mu, rstd, ln2_g, ln2_b, h2T);
  dwconv_tiled<<<dim3(32,16), b256, 0, stream>>>(h2T, w3, b3, w5, b5, apack);
  gemm_packed<64,32,2><<<dim3(128,8,2), b128, 0, stream>>>(apack, w1P, nullptr, nullptr, nullptr, pbuf);
  reduce_conv1<<<dim3(1024), b256, 0, stream>>>(pbuf, b1, x2, out);
}

// Round 25
// 126.726 us; speedup vs baseline: 1.0803x; 1.0123x over previous
//
#include <hip/hip_runtime.h>
#include <math.h>

#define N_TOK 4096
#define C_DIM 256
#define HEADS 8
#define HDIM  32
#define SCALE 0.17677669529663687f

typedef float f32x4 __attribute__((ext_vector_type(4)));
typedef float f32x2 __attribute__((ext_vector_type(2)));
typedef int   i32x4 __attribute__((ext_vector_type(4)));
typedef __bf16 bf16x8 __attribute__((ext_vector_type(8)));
typedef __bf16 bf16x2 __attribute__((ext_vector_type(2)));

#if defined(__has_builtin)
#if __has_builtin(__builtin_amdgcn_mfma_f32_16x16x32_bf16)
#define HAVE_MFMA_BUILTIN 1
#endif
#if __has_builtin(__builtin_amdgcn_fdot2_f32_bf16)
#define HAVE_DOT2 1
#endif
#endif

__device__ __forceinline__ unsigned short f2bf(float x){
  unsigned u = __float_as_uint(x);
  u += 0x7FFFu + ((u >> 16) & 1u);
  return (unsigned short)(u >> 16);
}

// packed fragment index: element (row m, col-k k) of a [16 x 32] tile
__device__ __forceinline__ size_t pk_idx(int m, int k, int KT){
  return ((size_t)(m >> 4)*KT + (k >> 5))*512 + (((m & 15) + 16*((k >> 3) & 3))*8 + (k & 7));
}

// order-preserving float->uint (monotone)
__device__ __forceinline__ unsigned f2key(float s){
  unsigned b = __float_as_uint(s);
  return b ^ ((unsigned)((int)b >> 31) | 0x80000000u);
}
__device__ __forceinline__ unsigned umax_(unsigned a, unsigned b){ return a > b ? a : b; }
__device__ __forceinline__ unsigned umin_(unsigned a, unsigned b){ return a < b ? a : b; }

#define KCMP(A,i,j) { unsigned h_ = umax_(A[i],A[j]); unsigned l_ = umin_(A[i],A[j]); A[i]=h_; A[j]=l_; }

__device__ __forceinline__ void sort8(unsigned (&k)[8]){
  KCMP(k,0,1) KCMP(k,2,3) KCMP(k,4,5) KCMP(k,6,7)
  KCMP(k,0,2) KCMP(k,1,3) KCMP(k,4,6) KCMP(k,5,7)
  KCMP(k,1,2) KCMP(k,5,6)
  KCMP(k,0,4) KCMP(k,1,5) KCMP(k,2,6) KCMP(k,3,7)
  KCMP(k,2,4) KCMP(k,3,5)
  KCMP(k,1,2) KCMP(k,3,4) KCMP(k,5,6)
}

__device__ __forceinline__ void mergetop8(unsigned (&a)[8], const unsigned (&b)[8]){
  #pragma unroll
  for (int j=0;j<8;++j) a[j] = umax_(a[j], b[7-j]);
  KCMP(a,0,4) KCMP(a,1,5) KCMP(a,2,6) KCMP(a,3,7)
  KCMP(a,0,2) KCMP(a,1,3) KCMP(a,4,6) KCMP(a,5,7)
  KCMP(a,0,1) KCMP(a,2,3) KCMP(a,4,5) KCMP(a,6,7)
}

template<int MLO, int MHI>
__device__ __forceinline__ void merge_keys(unsigned (&k)[8]){
  #pragma unroll
  for (int m=MLO; m<=MHI; m<<=1){
    unsigned o[8];
    #pragma unroll
    for (int j=0;j<8;++j) o[j] = (unsigned)__shfl_xor((int)k[j], m);
    #pragma unroll
    for (int j=0;j<8;++j) k[j] = umax_(k[j], o[7-j]);
    KCMP(k,0,4) KCMP(k,1,5) KCMP(k,2,6) KCMP(k,3,7)
    KCMP(k,0,2) KCMP(k,1,3) KCMP(k,4,6) KCMP(k,5,7)
    KCMP(k,0,1) KCMP(k,2,3) KCMP(k,4,5) KCMP(k,6,7)
  }
}

// D = A(16x32) * B(32x16) + C via v_mfma_f32_16x16x32_bf16.
__device__ __forceinline__ f32x4 mfma16(i32x4 a, i32x4 b, f32x4 c){
#ifdef HAVE_MFMA_BUILTIN
  return __builtin_amdgcn_mfma_f32_16x16x32_bf16(
      __builtin_bit_cast(bf16x8, a), __builtin_bit_cast(bf16x8, b), c, 0, 0, 0);
#else
  f32x4 d;
  asm volatile("v_mfma_f32_16x16x32_bf16 %0, %1, %2, %3\n\ts_nop 7\n\ts_nop 3"
               : "=&v"(d) : "v"(a), "v"(b), "v"(c));
  return d;
#endif
}

// ---- q-row context + exact f32 dot of a 32-elem bf16 K-row with it ----
#ifdef HAVE_DOT2
struct QCtx { unsigned q[16]; };
__device__ __forceinline__ void qload(QCtx& qc, const unsigned short* qrow){
  #pragma unroll
  for (int i=0;i<4;++i){
    i32x4 qv = *(const i32x4*)(qrow + i*8);
    #pragma unroll
    for (int j=0;j<4;++j) qc.q[i*4+j] = (unsigned)qv[j];
  }
}
__device__ __forceinline__ float dot32(const i32x4& k0, const i32x4& k1,
                                       const i32x4& k2, const i32x4& k3, const QCtx& qc){
  float s = 0.f;
  #pragma unroll
  for (int q=0;q<4;++q){
    const i32x4& kv = (q==0)?k0 : (q==1)?k1 : (q==2)?k2 : k3;
    #pragma unroll
    for (int j=0;j<4;++j)
      s = __builtin_amdgcn_fdot2_f32_bf16(__builtin_bit_cast(bf16x2, (unsigned)kv[j]),
                                          __builtin_bit_cast(bf16x2, qc.q[q*4+j]), s, false);
  }
  return s;
}
#else
struct QCtx { f32x2 q[16]; };
__device__ __forceinline__ void qload(QCtx& qc, const unsigned short* qrow){
  #pragma unroll
  for (int i=0;i<4;++i){
    i32x4 qv = *(const i32x4*)(qrow + i*8);
    #pragma unroll
    for (int j=0;j<4;++j){
      unsigned u = (unsigned)qv[j];
      f32x2 p; p.x = __uint_as_float(u << 16); p.y = __uint_as_float(u & 0xFFFF0000u);
      qc.q[i*4+j] = p;
    }
  }
}
__device__ __forceinline__ float dot32(const i32x4& k0, const i32x4& k1,
                                       const i32x4& k2, const i32x4& k3, const QCtx& qc){
  f32x2 acc = {0.f, 0.f};
  #pragma unroll
  for (int q=0;q<4;++q){
    const i32x4& kv = (q==0)?k0 : (q==1)?k1 : (q==2)?k2 : k3;
    #pragma unroll
    for (int j=0;j<4;++j){
      unsigned u = (unsigned)kv[j];
      f32x2 p; p.x = __uint_as_float(u << 16); p.y = __uint_as_float(u & 0xFFFF0000u);
      acc += p * qc.q[q*4+j];
    }
  }
  return acc.x + acc.y;
}
#endif

// ---------------- LayerNorm (one row of 256 per block), packed bf16 out ----------------
__global__ __launch_bounds__(256) void ln_kernel_pack(const float* __restrict__ x,
    const float* __restrict__ g, const float* __restrict__ b,
    unsigned short* __restrict__ outP)
{
  int row = blockIdx.x, c = threadIdx.x;
  float v = x[(size_t)row*C_DIM + c];
  float s1 = v, s2 = v*v;
  #pragma unroll
  for (int off=1; off<64; off<<=1){
    s1 += __shfl_xor(s1, off);
    s2 += __shfl_xor(s2, off);
  }
  __shared__ float r1[4], r2[4];
  int wv = c >> 6;
  if ((c & 63) == 0){ r1[wv] = s1; r2[wv] = s2; }
  __syncthreads();
  s1 = r1[0]+r1[1]+r1[2]+r1[3];
  s2 = r2[0]+r2[1]+r2[2]+r2[3];
  float mu  = s1 * (1.0f/C_DIM);
  float var = s2 * (1.0f/C_DIM) - mu*mu;
  float inv = 1.0f / sqrtf(var + 1e-5f);
  float o = (v - mu) * inv * g[c] + b[c];
  outP[pk_idx(row, c, 8)] = f2bf(o);
}

// ---------------- LN stats only: one wave per token ----------------
__global__ __launch_bounds__(256) void ln_stats(const float* __restrict__ x,
    float* __restrict__ mu, float* __restrict__ rstd)
{
  int token = blockIdx.x*4 + (threadIdx.x >> 6);
  int lane = threadIdx.x & 63;
  f32x4 v = *(const f32x4*)(x + (size_t)token*C_DIM + lane*4);
  float s1 = v[0]+v[1]+v[2]+v[3];
  float s2 = v[0]*v[0]+v[1]*v[1]+v[2]*v[2]+v[3]*v[3];
  #pragma unroll
  for (int off=1; off<64; off<<=1){
    s1 += __shfl_xor(s1, off);
    s2 += __shfl_xor(s2, off);
  }
  if (lane == 0){
    float m = s1 * (1.0f/C_DIM);
    float var = s2 * (1.0f/C_DIM) - m*m;
    mu[token] = m;
    rstd[token] = 1.0f / sqrtf(var + 1e-5f);
  }
}

// ---------------- fused normalize + 64x64 transpose: x2[tok][ch] -> h2T[ch][tok] ----------------
__global__ __launch_bounds__(256) void transpose_norm(const float* __restrict__ src,
    const float* __restrict__ mu, const float* __restrict__ rstd,
    const float* __restrict__ g, const float* __restrict__ b,
    float* __restrict__ dstF)
{
  __shared__ float t[64][65];
  int c0 = blockIdx.x*64, r0 = blockIdx.y*64;
  int x = threadIdx.x & 63, ys = threadIdx.x >> 6;
  float gg = g[c0 + x], bb = b[c0 + x];
  #pragma unroll
  for (int i=0;i<16;++i){
    int r = ys + i*4;
    int tok = r0 + r;
    float v = src[(size_t)tok*C_DIM + c0 + x];
    t[r][x] = (v - mu[tok]) * rstd[tok] * gg + bb;
  }
  __syncthreads();
  #pragma unroll
  for (int i=0;i<16;++i){
    int rr = ys + i*4;
    dstF[(size_t)(c0+rr)*N_TOK + r0 + x] = t[x][rr];
  }
}

// ---------------- fused weight prep + sumv zero: one dispatch ----------------
// blocks 0..1023: w1 pack; 1024..1039: q_w; 1040..1071: kv_w; 1072..1087: proj_w; 1088: zero sumv
__device__ __forceinline__ void tp_body(const float* __restrict__ src,
    unsigned short* __restrict__ dstP, int Cc, int nbase, int KT, int bx, int by)
{
  __shared__ float t[64][65];
  int c0 = bx*64, r0 = by*64;
  int x = threadIdx.x & 63, ys = threadIdx.x >> 6;
  #pragma unroll
  for (int i=0;i<16;++i){
    int r = ys + i*4;
    t[r][x] = src[(size_t)(r0+r)*Cc + c0 + x];
  }
  __syncthreads();
  #pragma unroll
  for (int i=0;i<16;++i){
    int rr = ys + i*4;
    int n = nbase + c0 + rr;
    int k = r0 + x;
    dstP[pk_idx(n, k, KT)] = f2bf(t[x][rr]);
  }
}

__global__ __launch_bounds__(256) void prep_weights(
    const float* __restrict__ w1, unsigned short* __restrict__ w1p,
    const float* __restrict__ q_w, const float* __restrict__ kv_w,
    const float* __restrict__ proj_w,
    unsigned short* __restrict__ wAllP, unsigned short* __restrict__ pwP,
    float* __restrict__ sumv)
{
  int b = blockIdx.x;
  if (b < 1024){
    int tid = threadIdx.x;
    int lane = tid >> 2;
    int j = (tid & 3) * 2;
    int n = (b >> 6)*16 + (lane & 15);
    int k = (b & 63)*32 + (lane >> 4)*8 + j;
    unsigned lo = f2bf(w1[(size_t)n*2048 + k]);
    unsigned hi = f2bf(w1[(size_t)n*2048 + k + 1]);
    *(unsigned*)(w1p + (size_t)b*512 + lane*8 + j) = lo | (hi << 16);
  } else if (b < 1040){
    int idx = b - 1024;                       // 4x4
    tp_body(q_w, wAllP, 256, 0, 8, idx & 3, idx >> 2);
  } else if (b < 1072){
    int idx = b - 1040;                       // 8x4
    tp_body(kv_w, wAllP, 512, 256, 8, idx & 7, idx >> 3);
  } else if (b < 1088){
    int idx = b - 1072;                       // 4x4
    tp_body(proj_w, pwP, 256, 0, 8, idx & 3, idx >> 2);
  } else {
    sumv[threadIdx.x] = 0.0f;                 // zero for qkv's atomic colsum
  }
}

#define LDT(p, i) (*(const i32x4*)((p) + (size_t)(i)*512))

// ---------------- packed-stream GEMM: sequential 1KB/wave tile loads, 4-deep ring ----------------
template<int KTT, int KTC, int NPAIR>
__global__ __launch_bounds__(128, 2) void gemm_packed(
    const unsigned short* __restrict__ Ap, const unsigned short* __restrict__ Bp,
    const float* __restrict__ bias, const float* __restrict__ resid,
    float* __restrict__ outF, float* __restrict__ pbuf)
{
  int wave = threadIdx.x >> 6, lane = threadIdx.x & 63;
  int l16 = lane & 15, lg = lane >> 4;
  int mt = blockIdx.x*2 + wave;
  int nt0 = blockIdx.y * NPAIR;
  int z = blockIdx.z;
  const unsigned short* ap  = Ap + ((size_t)mt*KTT  + z*KTC)*512 + lane*8;
  const unsigned short* bp0 = Bp + ((size_t)nt0*KTT + z*KTC)*512 + lane*8;
  const unsigned short* bp1 = (NPAIR > 1) ? Bp + ((size_t)(nt0+1)*KTT + z*KTC)*512 + lane*8 : bp0;
  f32x4 acc0 = {0.f,0.f,0.f,0.f}, acc1 = acc0;

  i32x4 A0 = LDT(ap,0), A1 = LDT(ap,1), A2 = LDT(ap,2), A3 = LDT(ap,3);
  i32x4 B0 = LDT(bp0,0), B1 = LDT(bp0,1), B2 = LDT(bp0,2), B3 = LDT(bp0,3);
  i32x4 C0, C1, C2, C3;
  if (NPAIR == 2){ C0 = LDT(bp1,0); C1 = LDT(bp1,1); C2 = LDT(bp1,2); C3 = LDT(bp1,3); }
  #pragma unroll
  for (int kt = 0; kt < KTC; ++kt){
    const int nk = (kt + 4 < KTC) ? (kt + 4) : (KTC - 1);
    switch (kt & 3){
      case 0: acc0 = mfma16(A0, B0, acc0); if (NPAIR==2) acc1 = mfma16(A0, C0, acc1);
              A0 = LDT(ap,nk); B0 = LDT(bp0,nk); if (NPAIR==2) C0 = LDT(bp1,nk); break;
      case 1: acc0 = mfma16(A1, B1, acc0); if (NPAIR==2) acc1 = mfma16(A1, C1, acc1);
              A1 = LDT(ap,nk); B1 = LDT(bp0,nk); if (NPAIR==2) C1 = LDT(bp1,nk); break;
      case 2: acc0 = mfma16(A2, B2, acc0); if (NPAIR==2) acc1 = mfma16(A2, C2, acc1);
              A2 = LDT(ap,nk); B2 = LDT(bp0,nk); if (NPAIR==2) C2 = LDT(bp1,nk); break;
      case 3: acc0 = mfma16(A3, B3, acc0); if (NPAIR==2) acc1 = mfma16(A3, C3, acc1);
              A3 = LDT(ap,nk); B3 = LDT(bp0,nk); if (NPAIR==2) C3 = LDT(bp1,nk); break;
    }
  }
  if (pbuf){
    float* pb = pbuf + (size_t)z * (N_TOK*C_DIM);
    #pragma unroll
    for (int f=0; f<NPAIR; ++f){
      f32x4 acc = f ? acc1 : acc0;
      int n = (nt0 + f)*16 + l16;
      #pragma unroll
      for (int r=0;r<4;++r)
        pb[(size_t)(mt*16 + lg*4 + r)*C_DIM + n] = acc[r];
    }
  } else {
    #pragma unroll
    for (int f=0; f<NPAIR; ++f){
      f32x4 acc = f ? acc1 : acc0;
      int n = (nt0 + f)*16 + l16;
      float bb = bias[n];
      #pragma unroll
      for (int r=0;r<4;++r){
        int m = mt*16 + lg*4 + r;
        float val = acc[r] + bb;
        if (resid) val += resid[(size_t)m*C_DIM + n];
        outF[(size_t)m*C_DIM + n] = val;
      }
    }
  }
}

// ---------------- fused q/kv/v packed GEMM (paired N-tiles, kpack direct, atomic colsum) ----
__global__ __launch_bounds__(128, 2) void gemm_qkv_packed(
    const unsigned short* __restrict__ Ap, const unsigned short* __restrict__ Bp,
    const float* __restrict__ q_b, const float* __restrict__ kv_b,
    unsigned short* __restrict__ qbf, unsigned short* __restrict__ kbf,
    float* __restrict__ vbuf, unsigned short* __restrict__ kpackW,
    float* __restrict__ sumv)
{
  int wave = threadIdx.x >> 6, lane = threadIdx.x & 63;
  int l16 = lane & 15, lg = lane >> 4;
  int mt = blockIdx.x*2 + wave;
  int nt0 = blockIdx.y * 2;
  const unsigned short* ap  = Ap + ((size_t)mt*8)*512 + lane*8;
  const unsigned short* bp0 = Bp + ((size_t)nt0*8)*512 + lane*8;
  const unsigned short* bp1 = Bp + ((size_t)(nt0+1)*8)*512 + lane*8;
  f32x4 acc0 = {0.f,0.f,0.f,0.f}, acc1 = acc0;
  i32x4 A0 = LDT(ap,0), A1 = LDT(ap,1), A2 = LDT(ap,2), A3 = LDT(ap,3);
  i32x4 B0 = LDT(bp0,0), B1 = LDT(bp0,1), B2 = LDT(bp0,2), B3 = LDT(bp0,3);
  i32x4 C0 = LDT(bp1,0), C1 = LDT(bp1,1), C2 = LDT(bp1,2), C3 = LDT(bp1,3);
  #pragma unroll
  for (int kt = 0; kt < 8; ++kt){
    const int nk = (kt + 4 < 8) ? (kt + 4) : 7;
    switch (kt & 3){
      case 0: acc0 = mfma16(A0, B0, acc0); acc1 = mfma16(A0, C0, acc1);
              A0 = LDT(ap,nk); B0 = LDT(bp0,nk); C0 = LDT(bp1,nk); break;
      case 1: acc0 = mfma16(A1, B1, acc0); acc1 = mfma16(A1, C1, acc1);
              A1 = LDT(ap,nk); B1 = LDT(bp0,nk); C1 = LDT(bp1,nk); break;
      case 2: acc0 = mfma16(A2, B2, acc0); acc1 = mfma16(A2, C2, acc1);
              A2 = LDT(ap,nk); B2 = LDT(bp0,nk); C2 = LDT(bp1,nk); break;
      case 3: acc0 = mfma16(A3, B3, acc0); acc1 = mfma16(A3, C3, acc1);
              A3 = LDT(ap,nk); B3 = LDT(bp0,nk); C3 = LDT(bp1,nk); break;
    }
  }
  #pragma unroll
  for (int f=0; f<2; ++f){
    f32x4 acc = f ? acc1 : acc0;
    int n = (nt0 + f)*16 + l16;
    float bb = (n < 256) ? q_b[n] : kv_b[n-256];
    float cs = 0.f;
    #pragma unroll
    for (int r=0;r<4;++r){
      int m = mt*16 + lg*4 + r;
      float val = acc[r] + bb;
      if (n < 256){
        qbf[(size_t)m*C_DIM + n] = f2bf(fmaxf(val, 0.f));
      } else if (n < 512){
        int ch = n - 256;
        unsigned short bv = f2bf(val);
        kbf[(size_t)m*C_DIM + ch] = bv;
        kpackW[((size_t)((ch >> 5)*256 + mt)*64 + (lg*4 + r) + 16*((ch >> 3) & 3))*8 + (ch & 7)] = bv;
      } else {
        vbuf[(size_t)m*C_DIM + (n-512)] = val;
        cs += val;
      }
    }
    if (n >= 512){
      // reduce over the wave's 16 rows (4 lane-groups), then one atomic per column
      cs += __shfl_xor(cs, 16);
      cs += __shfl_xor(cs, 32);
      if (lg == 0) atomicAdd(&sumv[n - 512], cs);
    }
  }
}

// ---------------- split-K reduce (2 partials): out = p0 + p1 + bias + resid ----------------
__global__ __launch_bounds__(256) void reduce_conv1(const float* __restrict__ pbuf,
    const float* __restrict__ bias, const float* __restrict__ resid,
    float* __restrict__ out)
{
  int i = (blockIdx.x*256 + threadIdx.x) * 4;
  f32x4 a = *(const f32x4*)(pbuf + i);
  f32x4 b = *(const f32x4*)(pbuf + (size_t)N_TOK*C_DIM + i);
  f32x4 r = *(const f32x4*)(resid + i);
  f32x4 bb = *(const f32x4*)(bias + (i & 255));
  *(f32x4*)(out + i) = a + b + r + bb;
}

// block = 32 q-rows x 4 waves; wave w scans packed K-tiles [w*64, w*64+64) sequentially,
// 2 q-fragments, 8-deep prefetch ring, IMMEDIATE fold (round-20-proven structure).
__global__ __launch_bounds__(256, 4) void attn_kernel(
    const unsigned short* __restrict__ qbf, const unsigned short* __restrict__ kbf,
    const unsigned short* __restrict__ kpack,
    const float* __restrict__ v, const float* __restrict__ sumv,
    unsigned short* __restrict__ outp)
{
  const int head = blockIdx.y;
  const int tid  = threadIdx.x;
  const int wave = tid >> 6, lane = tid & 63;
  const int l16 = lane & 15, lg = lane >> 4;
  const int row0 = blockIdx.x * 32;

  __shared__ unsigned ls[4][2][16][8];
  __shared__ int   gsel[32][8];
  __shared__ float lds_e[32][8];
  __shared__ int   lds_idx[32][8];
  __shared__ float lds_rd[32];

  // ---- phase 1 ----
  i32x4 qf0 = *(const i32x4*)(qbf + (size_t)(row0      + l16)*C_DIM + head*HDIM + lg*8);
  i32x4 qf1 = *(const i32x4*)(qbf + (size_t)(row0 + 16 + l16)*C_DIM + head*HDIM + lg*8);
  const f32x4 zacc = {0.f,0.f,0.f,0.f};
  const int tbase = wave * 64;
  const unsigned short* kp = kpack + ((size_t)(head*256 + tbase)*64 + lane)*8;

  i32x4 kr0 = *(const i32x4*)(kp);
  i32x4 kr1 = *(const i32x4*)(kp + 512);
  i32x4 kr2 = *(const i32x4*)(kp + 1024);
  i32x4 kr3 = *(const i32x4*)(kp + 1536);
  i32x4 kr4 = *(const i32x4*)(kp + 2048);
  i32x4 kr5 = *(const i32x4*)(kp + 2560);
  i32x4 kr6 = *(const i32x4*)(kp + 3072);
  i32x4 kr7 = *(const i32x4*)(kp + 3584);

  unsigned t0[8], t1[8], g80[8], g81[8];
  #pragma unroll
  for (int j=0;j<8;++j){ t0[j]=0u; t1[j]=0u; }
  const int codebase = 511 - wave*128 - lg;
  #pragma unroll
  for (int g = 0; g < 32; ++g){
    float gm0 = -3e38f, gm1 = -3e38f;
    #pragma unroll
    for (int u = 0; u < 2; ++u){
      const int t = g*2 + u;
      #define USE_SLOT(S) { \
        f32x4 a0 = mfma16(S, qf0, zacc); \
        f32x4 a1 = mfma16(S, qf1, zacc); \
        S = *(const i32x4*)(kp + (size_t)(t+8)*512); \
        gm0 = fmaxf(gm0, fmaxf(fmaxf(a0[0],a0[1]), fmaxf(a0[2],a0[3]))); \
        gm1 = fmaxf(gm1, fmaxf(fmaxf(a1[0],a1[1]), fmaxf(a1[2],a1[3]))); }
      switch (t & 7){
        case 0: USE_SLOT(kr0); break;
        case 1: USE_SLOT(kr1); break;
        case 2: USE_SLOT(kr2); break;
        case 3: USE_SLOT(kr3); break;
        case 4: USE_SLOT(kr4); break;
        case 5: USE_SLOT(kr5); break;
        case 6: USE_SLOT(kr6); break;
        case 7: USE_SLOT(kr7); break;
      }
      #undef USE_SLOT
    }
    unsigned code = (unsigned)(codebase - g*4);
    g80[g & 7] = (f2key(gm0) & 0xFFFFFE00u) | code;
    g81[g & 7] = (f2key(gm1) & 0xFFFFFE00u) | code;
    if ((g & 7) == 7){
      sort8(g80); mergetop8(t0, g80);
      sort8(g81); mergetop8(t1, g81);
    }
  }
  merge_keys<16,32>(t0);
  merge_keys<16,32>(t1);

  if (lg == 0){
    #pragma unroll
    for (int j=0;j<8;++j){ ls[wave][0][l16][j]=t0[j]; ls[wave][1][l16][j]=t1[j]; }
  }
  __syncthreads();

  if (wave < 2){
    unsigned mk[8];
    #pragma unroll
    for (int j=0;j<8;++j) mk[j] = ls[lg][wave][l16][j];
    merge_keys<16,32>(mk);
    if (lg == 0){
      #pragma unroll
      for (int j=0;j<8;++j){
        int gid = 511 - (int)(mk[j] & 511u);
        gsel[wave*16 + l16][j] = (gid >> 2)*32 + (gid & 3)*4;
      }
    }
  }
  __syncthreads();

  // ---- phase 2 ----
  const int prow = tid >> 3;
  const int sub  = tid & 7;
  QCtx qc;
  qload(qc, qbf + (size_t)(row0 + prow)*C_DIM + head*HDIM);
  const int base = gsel[prow][sub];
  const unsigned short* kh = kbf + head*HDIM;
  #define COLOF(c) (base + (((c) >> 2) << 4) + ((c) & 3))
  unsigned sv[8];
  #pragma unroll
  for (int j=0;j<8;++j) sv[j] = 0u;
  i32x4 A0,A1,A2,A3, B0,B1,B2,B3;
  { const unsigned short* p = kh + (size_t)COLOF(0)*C_DIM;
    A0 = *(const i32x4*)(p); A1 = *(const i32x4*)(p+8); A2 = *(const i32x4*)(p+16); A3 = *(const i32x4*)(p+24); }
  { const unsigned short* p = kh + (size_t)COLOF(1)*C_DIM;
    B0 = *(const i32x4*)(p); B1 = *(const i32x4*)(p+8); B2 = *(const i32x4*)(p+16); B3 = *(const i32x4*)(p+24); }
  #pragma unroll
  for (int c = 0; c < 8; ++c){
    float s;
    if ((c & 1) == 0){
      s = dot32(A0,A1,A2,A3, qc);
      if (c + 2 < 8){
        const unsigned short* p = kh + (size_t)COLOF(c+2)*C_DIM;
        A0 = *(const i32x4*)(p); A1 = *(const i32x4*)(p+8); A2 = *(const i32x4*)(p+16); A3 = *(const i32x4*)(p+24);
      }
    } else {
      s = dot32(B0,B1,B2,B3, qc);
      if (c + 2 < 8){
        const unsigned short* p = kh + (size_t)COLOF(c+2)*C_DIM;
        B0 = *(const i32x4*)(p); B1 = *(const i32x4*)(p+8); B2 = *(const i32x4*)(p+16); B3 = *(const i32x4*)(p+24);
      }
    }
    int col = COLOF(c);
    unsigned kk = (f2key(s) & 0xFFFFF000u) | (unsigned)(4095 - col);
    #pragma unroll
    for (int j=0;j<8;++j){ unsigned h = umax_(sv[j], kk); kk = umin_(sv[j], kk); sv[j] = h; }
  }
  #undef COLOF
  merge_keys<1,4>(sv);

  {
    int col = 4095 - (int)(sv[sub] & 4095u);
    const unsigned short* krow = kh + (size_t)col*C_DIM;
    i32x4 k0 = *(const i32x4*)(krow);
    i32x4 k1 = *(const i32x4*)(krow+8);
    i32x4 k2 = *(const i32x4*)(krow+16);
    i32x4 k3 = *(const i32x4*)(krow+24);
    float s = dot32(k0,k1,k2,k3, qc);
    lds_e[prow][sub] = expm1f(s*SCALE);
    lds_idx[prow][sub] = col;
  }
  __syncthreads();

  if (tid < 32){
    float den = 4096.0f;
    #pragma unroll
    for (int j=0;j<8;++j) den += lds_e[tid][j];
    lds_rd[tid] = 1.0f / den;
  }
  __syncthreads();

  // ---- phase 3: PV; write packed fragment layout for proj GEMM ----
  #pragma unroll
  for (int it=0; it<4; ++it){
    int flat = it*256 + tid;
    int rl = flat >> 5, d = flat & 31;
    float num = sumv[head*HDIM + d];
    #pragma unroll
    for (int j=0;j<8;++j)
      num += lds_e[rl][j] * v[(size_t)lds_idx[rl][j]*C_DIM + head*HDIM + d];
    int row = row0 + rl;
    outp[pk_idx(row, head*HDIM + d, 8)] = f2bf(num * lds_rd[rl]);
  }
}

// ---------------- LDS-tiled grouped dwconv 3x3 & 5x5 -> packed A (KT=64) ----------------
__global__ __launch_bounds__(256) void dwconv_tiled(const float* __restrict__ img,
    const float* __restrict__ w3, const float* __restrict__ b3,
    const float* __restrict__ w5, const float* __restrict__ b5,
    unsigned short* __restrict__ apack)
{
  __shared__ float tile[8][513];
  int bx = blockIdx.x;
  int ic0 = bx * 8;
  int py0 = blockIdx.y * 4;
  int tid = threadIdx.x;

  #pragma unroll
  for (int i = 0; i < 16; ++i){
    int idx = i*256 + tid;
    int ch  = idx >> 9;
    int rem = idx & 511;
    int ry  = rem >> 6, x = rem & 63;
    int y   = py0 - 2 + ry;
    float v = (y >= 0 && y < 64) ? img[(size_t)(ic0+ch)*4096 + y*64 + x] : 0.f;
    tile[ch][ry*64 + x] = v;
  }
  __syncthreads();

  int o_l  = tid & 31;
  int p_l  = tid >> 5;
  int ic_l = o_l >> 2;
  int o3   = ic0*4 + o_l;
  const float* pl = tile[ic_l];

  float W3[9], W5[25];
  #pragma unroll
  for (int i=0;i<9;++i)  W3[i] = w3[o3*9+i];
  #pragma unroll
  for (int i=0;i<25;++i) W5[i] = w5[o3*25+i];
  float bb3 = b3[o3], bb5 = b5[o3];

  int lane_lo = 16*((o_l >> 3) & 3);
  int elem    = o_l & 7;

  #pragma unroll 4
  for (int it = 0; it < 32; ++it){
    int pp = it*8 + p_l;
    int ly = (pp >> 6) + 2;
    int x  = pp & 63;
    float a3 = bb3, a5 = bb5;
    #pragma unroll
    for (int dy=-2; dy<=2; ++dy){
      #pragma unroll
      for (int dx=-2; dx<=2; ++dx){
        int xx = x + dx;
        float iv = (xx >= 0 && xx < 64) ? pl[(ly+dy)*64 + xx] : 0.f;
        a5 += W5[(dy+2)*5 + dx+2] * iv;
        if (dy>=-1 && dy<=1 && dx>=-1 && dx<=1)
          a3 += W3[(dy+1)*3 + dx+1] * iv;
      }
    }
    int p = (py0 + (pp>>6))*64 + x;
    size_t ad3 = ((size_t)(p >> 4)*64 + bx)*512 + ((p & 15) + lane_lo)*8 + elem;
    apack[ad3]          = f2bf(fmaxf(a3, 0.f));
    apack[ad3 + 32*512] = f2bf(fmaxf(a5, 0.f));
  }
}

extern "C" void kernel_launch(void* const* d_in, const int* in_sizes, int n_in,
                              void* d_out, int out_size, void* d_ws, size_t ws_size,
                              hipStream_t stream)
{
  (void)in_sizes; (void)n_in; (void)out_size; (void)ws_size;
  const float* x      = (const float*)d_in[0];
  const float* ln1_g  = (const float*)d_in[3];
  const float* ln1_b  = (const float*)d_in[4];
  const float* q_w    = (const float*)d_in[5];
  const float* q_b    = (const float*)d_in[6];
  const float* kv_w   = (const float*)d_in[7];
  const float* kv_b   = (const float*)d_in[8];
  const float* proj_w = (const float*)d_in[9];
  const float* proj_b = (const float*)d_in[10];
  const float* ln2_g  = (const float*)d_in[11];
  const float* ln2_b  = (const float*)d_in[12];
  const float* w3     = (const float*)d_in[13];
  const float* b3     = (const float*)d_in[14];
  const float* w5     = (const float*)d_in[15];
  const float* b5     = (const float*)d_in[16];
  const float* w1     = (const float*)d_in[17];
  const float* b1     = (const float*)d_in[18];
  float* out = (float*)d_out;
  char* ws = (char*)d_ws;

  unsigned short* wAllP = (unsigned short*)(ws + 0x0);       // 384 KB packed qkv weights
  unsigned short* pwP   = (unsigned short*)(ws + 0x60000);   // 128 KB packed proj weights
  unsigned short* w1P   = (unsigned short*)(ws + 0x80000);   // 1 MB packed conv1 weights
  unsigned short* kpack = (unsigned short*)(ws + 0x180000);  // 2 MB (written by qkv; dead after attn)
  unsigned short* qbf   = (unsigned short*)(ws + 0x380000);  // 2 MB row-major
  unsigned short* kbf   = (unsigned short*)(ws + 0x580000);  // 2 MB row-major
  float*          vbuf  = (float*)(ws + 0x780000);           // 4 MB
  unsigned short* opack = (unsigned short*)(ws + 0xB80000);  // 2 MB packed attn out
  float*          x2    = (float*)(ws + 0xD80000);           // 4 MB
  unsigned short* hpack = (unsigned short*)(ws + 0xD80000);  // 2 MB packed ln1 out (dead before x2 written)
  float*          sumv  = (float*)(ws + 0x1180000);          // 1 KB (zeroed by prep_weights)
  float*          mu    = (float*)(ws + 0x11A0000);          // 16 KB
  float*          rstd  = (float*)(ws + 0x11A4000);          // 16 KB
  float*          h2T   = (float*)(ws + 0x580000);           // 4 MB (kbf+vbuf-lo dead after attn)
  float*          pbuf  = (float*)(ws + 0x180000);           // 8 MB (kpack+qbf dead by conv1)
  unsigned short* apack = (unsigned short*)(ws + 0x1200000); // 16 MB packed dwconv out

  dim3 b256(256), b128(128);

  // fused weight prep + sumv zero (1 dispatch)
  prep_weights<<<dim3(1089), b256, 0, stream>>>(w1, w1P, q_w, kv_w, proj_w, wAllP, pwP, sumv);

  // attention branch (colsum fused into qkv epilogue)
  ln_kernel_pack<<<dim3(4096), b256, 0, stream>>>(x, ln1_g, ln1_b, hpack);
  gemm_qkv_packed<<<dim3(128,24), b128, 0, stream>>>(hpack, wAllP, q_b, kv_b, qbf, kbf, vbuf, kpack, sumv);
  attn_kernel<<<dim3(128,8), b256, 0, stream>>>(qbf, kbf, kpack, vbuf, sumv, opack);
  gemm_packed<8,8,2><<<dim3(128,8,1), b128, 0, stream>>>(opack, pwP, proj_b, x, x2, nullptr);

  // MSFN branch (LN2 fused into transpose)
  ln_stats<<<dim3(1024), b256, 0, stream>>>(x2, mu, rstd);
  transpose_norm<<<dim3(4,64), b256, 0, stream>>>(x2, mu, rstd, ln2_g, ln2_b, h2T);
  dwconv_tiled<<<dim3(32,16), b256, 0, stream>>>(h2T, w3, b3, w5, b5, apack);
  gemm_packed<64,32,2><<<dim3(128,8,2), b128, 0, stream>>>(apack, w1P, nullptr, nullptr, nullptr, pbuf);
  reduce_conv1<<<dim3(1024), b256, 0, stream>>>(pbuf, b1, x2, out);
}